// Round 2
// baseline (3670.008 us; speedup 1.0000x reference)
//
#include <hip/hip_runtime.h>
#include <hip/hip_bf16.h>

typedef unsigned short ushort_t;
typedef unsigned int uint_t;

__device__ __forceinline__ float bf2f(ushort_t u){
    union { unsigned int i; float f; } c; c.i = ((unsigned int)u) << 16; return c.f;
}
__device__ __forceinline__ ushort_t f2bf(float x){
    union { float f; unsigned int i; } c; c.f = x;
    unsigned int i = c.i;
    return (ushort_t)((i + 0x7fffu + ((i >> 16) & 1u)) >> 16);
}
__device__ __forceinline__ float relu_f(float x){ return fmaxf(x, 0.0f); }
__device__ __forceinline__ float sigmoid_f(float x){ return 1.0f / (1.0f + __expf(-x)); }

#define NT   2048      // T*B
#define TT   64

// ---------------- prep: build WihT (533x512 fp32: 532 rows of Wih^T + fused bias row), init bar ----------------
__global__ __launch_bounds__(256) void prep_kernel(
    const float* __restrict__ Wih, const float* __restrict__ bih,
    const float* __restrict__ bhh, float* __restrict__ WihTc, int* __restrict__ bar)
{
    int i = blockIdx.x * 256 + threadIdx.x;
    if (blockIdx.x == 0 && threadIdx.x == 0) { bar[0] = 0; bar[1] = 0; }
    if (i < 533 * 512) {
        int k = i >> 9, j = i & 511;
        float v;
        if (k < 532) v = Wih[j * 532 + k];
        else         v = bih[j] + bhh[j];
        WihTc[i] = v;
    }
}

// ---------------- fused convs: one block per sample; conv1/conv2 in LDS, conv3 -> out3T[k][n] bf16 ----------------
__global__ __launch_bounds__(256) void convs_kernel(
    const float* __restrict__ img,
    const float* __restrict__ W1, const float* __restrict__ b1,
    const float* __restrict__ W2, const float* __restrict__ b2,
    const float* __restrict__ W3, const float* __restrict__ b3,
    ushort_t* __restrict__ out3T)
{
    __shared__ float c1[400 * 33];   // 52.8 KB, stride 33 breaks 32-float same-bank stride
    __shared__ float c2[81 * 65];    // 21.1 KB, stride 65
    int n = blockIdx.x, tid = threadIdx.x;
    const float* imgn = img + (size_t)n * (84 * 84 * 3);

    // conv1: 84x84x3 -> 20x20x32, k=8 s=4
    for (int px = tid; px < 400; px += 256) {
        int oy = px / 20, ox = px % 20;
        float acc[32];
        #pragma unroll
        for (int oc = 0; oc < 32; oc++) acc[oc] = b1[oc];
        const float* base = imgn + (oy * 4 * 84 + ox * 4) * 3;
        for (int ky = 0; ky < 8; ky++) {
            const float* row = base + ky * 84 * 3;
            #pragma unroll
            for (int t = 0; t < 24; t++) {       // kx*3+ic
                float pix = row[t];
                const float* wp = W1 + (ky * 24 + t) * 32;
                #pragma unroll
                for (int oc = 0; oc < 32; oc++) acc[oc] = fmaf(pix, wp[oc], acc[oc]);
            }
        }
        #pragma unroll
        for (int oc = 0; oc < 32; oc++) c1[px * 33 + oc] = relu_f(acc[oc]);
    }
    __syncthreads();

    // conv2: 20x20x32 -> 9x9x64, k=4 s=2 ; 81 px x 4 channel-quarters
    for (int idx = tid; idx < 324; idx += 256) {
        int px = idx >> 2, q = idx & 3;
        int oy = px / 9, ox = px % 9;
        int oc0 = q * 16;
        float acc[16];
        #pragma unroll
        for (int j = 0; j < 16; j++) acc[j] = b2[oc0 + j];
        for (int ky = 0; ky < 4; ky++) {
            for (int kx = 0; kx < 4; kx++) {
                const float* crow = c1 + ((oy * 2 + ky) * 20 + (ox * 2 + kx)) * 33;
                const float* wk = W2 + ((ky * 4 + kx) * 32) * 64 + oc0;
                #pragma unroll
                for (int ic = 0; ic < 32; ic++) {
                    float pix = crow[ic];
                    const float* wp = wk + ic * 64;
                    #pragma unroll
                    for (int j = 0; j < 16; j++) acc[j] = fmaf(pix, wp[j], acc[j]);
                }
            }
        }
        #pragma unroll
        for (int j = 0; j < 16; j++) c2[px * 65 + oc0 + j] = relu_f(acc[j]);
    }
    __syncthreads();

    // conv3: 9x9x64 -> 7x7x64, k=3 s=1 ; 49 px x 4 quarters; write transposed bf16
    for (int idx = tid; idx < 196; idx += 256) {
        int px = idx >> 2, q = idx & 3;
        int oy = px / 7, ox = px % 7;
        int oc0 = q * 16;
        float acc[16];
        #pragma unroll
        for (int j = 0; j < 16; j++) acc[j] = b3[oc0 + j];
        for (int ky = 0; ky < 3; ky++) {
            for (int kx = 0; kx < 3; kx++) {
                const float* crow = c2 + ((oy + ky) * 9 + (ox + kx)) * 65;
                const float* wk = W3 + ((ky * 3 + kx) * 64) * 64 + oc0;
                #pragma unroll
                for (int ic = 0; ic < 64; ic++) {
                    float pix = crow[ic];
                    const float* wp = wk + ic * 64;
                    #pragma unroll
                    for (int j = 0; j < 16; j++) acc[j] = fmaf(pix, wp[j], acc[j]);
                }
            }
        }
        int k0 = px * 64 + oc0;
        #pragma unroll
        for (int j = 0; j < 16; j++)
            out3T[(size_t)(k0 + j) * NT + n] = f2bf(relu_f(acc[j]));
    }
}

// ---------------- FC: feat = relu(out3 @ Wfc + bfc); A is out3T[k][n] bf16 -> featT[j][n] bf16 ----------------
__global__ __launch_bounds__(256) void fc_kernel(
    const ushort_t* __restrict__ A,      // [3136][2048]
    const float* __restrict__ Wfc, const float* __restrict__ bfc,
    ushort_t* __restrict__ featT)        // [512][2048]
{
    int bid = blockIdx.x;                // 512 = 8 n-blocks x 64 j-groups
    int jg = bid & 63, nb = bid >> 6;
    int n = nb * 256 + threadIdx.x;
    int j0 = jg * 8;
    float acc[8];
    #pragma unroll
    for (int j = 0; j < 8; j++) acc[j] = bfc[j0 + j];
    for (int k = 0; k < 3136; k++) {
        float a = bf2f(A[(size_t)k * NT + n]);
        const float* wp = Wfc + (size_t)k * 512 + j0;
        #pragma unroll
        for (int j = 0; j < 8; j++) acc[j] = fmaf(a, wp[j], acc[j]);
    }
    #pragma unroll
    for (int j = 0; j < 8; j++)
        featT[(size_t)(j0 + j) * NT + n] = f2bf(relu_f(acc[j]));
}

// ---------------- gates_x: gx[n][j] = feat @ WihT + onehot rows + bias row (fp32) ----------------
__global__ __launch_bounds__(256) void gates_kernel(
    const ushort_t* __restrict__ featT, const float* __restrict__ WihTc,
    const int* __restrict__ pos, float* __restrict__ gx)
{
    int bid = blockIdx.x;                // 512 = 8 n-blocks x 64 j-groups
    int jg = bid & 63, nb = bid >> 6;
    int n = nb * 256 + threadIdx.x;
    int j0 = jg * 8;
    float acc[8];
    const float* bias = WihTc + 532 * 512 + j0;
    int p0 = pos[2 * n], p1 = pos[2 * n + 1];
    const float* r0 = WihTc + (size_t)(512 + p0) * 512 + j0;
    const float* r1 = WihTc + (size_t)(522 + p1) * 512 + j0;
    #pragma unroll
    for (int j = 0; j < 8; j++) acc[j] = bias[j] + r0[j] + r1[j];
    for (int k = 0; k < 512; k++) {
        float a = bf2f(featT[(size_t)k * NT + n]);
        const float* wp = WihTc + (size_t)k * 512 + j0;
        #pragma unroll
        for (int j = 0; j < 8; j++) acc[j] = fmaf(a, wp[j], acc[j]);
    }
    float* o = gx + (size_t)n * 512 + j0;
    #pragma unroll
    for (int j = 0; j < 8; j++) o[j] = acc[j];
}

// ---------------- LSTM scan: 16 blocks x 256, device-scope grid barrier ----------------
__device__ __forceinline__ void grid_barrier(int* bar, int nblocks){
    __syncthreads();
    if (threadIdx.x == 0) {
        int gen = __hip_atomic_load(&bar[1], __ATOMIC_ACQUIRE, __HIP_MEMORY_SCOPE_AGENT);
        int prev = __hip_atomic_fetch_add(&bar[0], 1, __ATOMIC_ACQ_REL, __HIP_MEMORY_SCOPE_AGENT);
        if (prev == nblocks - 1) {
            __hip_atomic_store(&bar[0], 0, __ATOMIC_RELAXED, __HIP_MEMORY_SCOPE_AGENT);
            __hip_atomic_fetch_add(&bar[1], 1, __ATOMIC_ACQ_REL, __HIP_MEMORY_SCOPE_AGENT);
        } else {
            while (__hip_atomic_load(&bar[1], __ATOMIC_ACQUIRE, __HIP_MEMORY_SCOPE_AGENT) == gen) {
                __builtin_amdgcn_s_sleep(4);
            }
        }
    }
    __syncthreads();
}

__global__ __launch_bounds__(256) void lstm_kernel(
    const float* __restrict__ gx, const float* __restrict__ Whh,
    const int* __restrict__ done, const float* __restrict__ h0,
    const float* __restrict__ c0,
    float* __restrict__ hg0, float* __restrict__ hg1,
    ushort_t* __restrict__ hs, float* __restrict__ out, int* __restrict__ bar)
{
    __shared__ float whh_s[32][132];   // rows: j = g*128 + bx*8 + hl
    __shared__ float h_s[32][132];     // masked h
    int tid = threadIdx.x, bx = blockIdx.x;

    for (int e = tid; e < 32 * 128; e += 256) {
        int rl = e >> 7, col = e & 127;
        int g = rl >> 3, hl = rl & 7;
        int j = g * 128 + bx * 8 + hl;
        whh_s[rl][col] = Whh[j * 128 + col];
    }
    int bb = tid >> 3, hl = tid & 7;
    int hid = bx * 8 + hl;
    float c = c0[bb * 128 + hid];
    if (bx == 0) {
        for (int e = tid; e < 4096; e += 256) hg0[e] = h0[e];
    }
    grid_barrier(bar, 16);

    float h = 0.0f;
    for (int t = 0; t < TT; t++) {
        const float* hr = (t & 1) ? hg1 : hg0;
        float* hw       = (t & 1) ? hg0 : hg1;
        for (int e = tid; e < 4096; e += 256) {
            int b = e >> 7;
            float m = 1.0f - (float)done[t * 32 + b];
            h_s[b][e & 127] = hr[e] * m;
        }
        __syncthreads();
        float m_own = 1.0f - (float)done[t * 32 + bb];
        c *= m_own;
        const float* gxr = gx + (size_t)(t * 32 + bb) * 512;
        float g0 = gxr[0 * 128 + hid];
        float g1 = gxr[1 * 128 + hid];
        float g2 = gxr[2 * 128 + hid];
        float g3 = gxr[3 * 128 + hid];
        #pragma unroll
        for (int k = 0; k < 128; k += 4) {
            float4 hv = *(const float4*)&h_s[bb][k];
            float4 w0 = *(const float4*)&whh_s[0 + hl][k];
            float4 w1 = *(const float4*)&whh_s[8 + hl][k];
            float4 w2 = *(const float4*)&whh_s[16 + hl][k];
            float4 w3 = *(const float4*)&whh_s[24 + hl][k];
            g0 += hv.x * w0.x + hv.y * w0.y + hv.z * w0.z + hv.w * w0.w;
            g1 += hv.x * w1.x + hv.y * w1.y + hv.z * w1.z + hv.w * w1.w;
            g2 += hv.x * w2.x + hv.y * w2.y + hv.z * w2.z + hv.w * w2.w;
            g3 += hv.x * w3.x + hv.y * w3.y + hv.z * w3.z + hv.w * w3.w;
        }
        float ig = sigmoid_f(g0);
        float fg = sigmoid_f(g1);
        float gg = tanhf(g2);
        float og = sigmoid_f(g3);
        c = fg * c + ig * gg;
        h = og * tanhf(c);
        hw[bb * 128 + hid] = h;
        hs[(size_t)(t * 32 + bb) * 128 + hid] = f2bf(h);
        grid_barrier(bar, 16);
    }
    // final h, c -> d_out (fp32 element offsets)
    out[12288 + bb * 128 + hid] = h;
    out[16384 + bb * 128 + hid] = c;
}

// ---------------- heads: logits (2048x5), v (2048) ----------------
__global__ __launch_bounds__(256) void heads_kernel(
    const ushort_t* __restrict__ hs, const float* __restrict__ Wp,
    const float* __restrict__ bp, const float* __restrict__ Wv,
    const float* __restrict__ bv, float* __restrict__ out)
{
    int id = blockIdx.x * 256 + threadIdx.x;   // 12288 = 2048*6
    int n = id / 6, q = id % 6;
    const ushort_t* hrow = hs + (size_t)n * 128;
    if (q < 5) {
        float acc = bp[q];
        for (int k = 0; k < 128; k++) acc = fmaf(bf2f(hrow[k]), Wp[k * 5 + q], acc);
        out[n * 5 + q] = acc;
    } else {
        float acc = bv[0];
        for (int k = 0; k < 128; k++) acc = fmaf(bf2f(hrow[k]), Wv[k], acc);
        out[10240 + n] = acc;
    }
}

extern "C" void kernel_launch(void* const* d_in, const int* in_sizes, int n_in,
                              void* d_out, int out_size, void* d_ws, size_t ws_size,
                              hipStream_t stream) {
    const float* image = (const float*)d_in[0];
    const int*   pos   = (const int*)d_in[1];
    const int*   done  = (const int*)d_in[2];
    const float* h0    = (const float*)d_in[3];
    const float* c0    = (const float*)d_in[4];
    const float* W1    = (const float*)d_in[5];
    const float* b1    = (const float*)d_in[6];
    const float* W2    = (const float*)d_in[7];
    const float* b2    = (const float*)d_in[8];
    const float* W3    = (const float*)d_in[9];
    const float* b3    = (const float*)d_in[10];
    const float* Wfc   = (const float*)d_in[11];
    const float* bfc   = (const float*)d_in[12];
    const float* Wih   = (const float*)d_in[13];
    const float* Whh   = (const float*)d_in[14];
    const float* bih   = (const float*)d_in[15];
    const float* bhh   = (const float*)d_in[16];
    const float* Wp    = (const float*)d_in[17];
    const float* bp    = (const float*)d_in[18];
    const float* Wv    = (const float*)d_in[19];
    const float* bv    = (const float*)d_in[20];

    char* ws = (char*)d_ws;
    float*    WihTc = (float*)(ws + 0);            // 1,091,584 B
    ushort_t* out3T = (ushort_t*)(ws + 1091584);   // 12,845,056 B -> ends 13,936,640
    ushort_t* featT = (ushort_t*)(ws + 13936640);  // 2,097,152 B  -> ends 16,033,792
    float*    gx    = (float*)(ws + 16033792);     // 4,194,304 B  -> ends 20,228,096
    ushort_t* hs    = (ushort_t*)(ws + 20228096);  // 524,288 B    -> ends 20,752,384
    float*    hg0   = (float*)(ws + 20752384);     // 16,384 B
    float*    hg1   = (float*)(ws + 20768768);     // 16,384 B
    int*      bar   = (int*)(ws + 20785152);       // 8 B

    float* out = (float*)d_out;

    prep_kernel<<<1066, 256, 0, stream>>>(Wih, bih, bhh, WihTc, bar);
    convs_kernel<<<2048, 256, 0, stream>>>(image, W1, b1, W2, b2, W3, b3, out3T);
    fc_kernel<<<512, 256, 0, stream>>>(out3T, Wfc, bfc, featT);
    gates_kernel<<<512, 256, 0, stream>>>(featT, WihTc, pos, gx);
    lstm_kernel<<<16, 256, 0, stream>>>(gx, Whh, done, h0, c0, hg0, hg1, hs, out, bar);
    heads_kernel<<<48, 256, 0, stream>>>(hs, Wp, bp, Wv, bv, out);
}

// Round 3
// 1216.348 us; speedup vs baseline: 3.0172x; 3.0172x over previous
//
#include <hip/hip_runtime.h>

typedef unsigned short ushort_t;
typedef unsigned int uint_t;

__device__ __forceinline__ float bf2f(ushort_t u){
    union { uint_t i; float f; } c; c.i = ((uint_t)u) << 16; return c.f;
}
__device__ __forceinline__ ushort_t f2bf(float x){
    union { float f; uint_t i; } c; c.f = x;
    uint_t i = c.i;
    return (ushort_t)((i + 0x7fffu + ((i >> 16) & 1u)) >> 16);
}
__device__ __forceinline__ uint_t pack2(float a, float b){
    return (uint_t)f2bf(a) | ((uint_t)f2bf(b) << 16);
}
__device__ __forceinline__ float relu_f(float x){ return fmaxf(x, 0.0f); }
__device__ __forceinline__ float sigmoid_f(float x){ return 1.0f / (1.0f + __expf(-x)); }

#define NT 2048
#define TT 64

// ---------------- prep: build WihT (533x512 fp32: 532 rows of Wih^T + fused bias row) ----------------
__global__ __launch_bounds__(256) void prep_kernel(
    const float* __restrict__ Wih, const float* __restrict__ bih,
    const float* __restrict__ bhh, float* __restrict__ WihTc)
{
    int i = blockIdx.x * 256 + threadIdx.x;
    if (i < 533 * 512) {
        int k = i >> 9, j = i & 511;
        float v;
        if (k < 532) v = Wih[j * 532 + k];
        else         v = bih[j] + bhh[j];
        WihTc[i] = v;
    }
}

// ---------------- conv1: 84x84x3 -> 20x20x32, k=8 s=4 ; image staged in LDS bf16 ----------------
// block per sample (half-batch launches), out c1g[n][400][32] bf16
__global__ __launch_bounds__(256) void conv1_kernel(
    const float* __restrict__ img, const float* __restrict__ W1,
    const float* __restrict__ b1, ushort_t* __restrict__ c1g)
{
    __shared__ ushort_t img_s[21168];   // 84*84*3 bf16 = 42336 B -> 3 blocks/CU
    int n = blockIdx.x, tid = threadIdx.x;
    const float2* ip = (const float2*)(img + (size_t)n * 21168);
    uint_t* ls = (uint_t*)img_s;
    for (int i = tid; i < 10584; i += 256) { float2 v = ip[i]; ls[i] = pack2(v.x, v.y); }
    __syncthreads();

    for (int pass = 0; pass < 2; pass++) {
        int px = pass * 256 + tid;
        if (px < 400) {
            int oy = px / 20, ox = px % 20;
            float acc[32];
            #pragma unroll
            for (int oc = 0; oc < 32; oc++) acc[oc] = b1[oc];
            for (int ky = 0; ky < 8; ky++) {
                int base = ((oy * 4 + ky) * 84 + ox * 4) * 3;
                const float* wk = W1 + ky * 768;            // (ky*8+kx)*3+ic -> ky*24 + t
                #pragma unroll
                for (int t = 0; t < 24; t++) {
                    float pix = bf2f(img_s[base + t]);
                    const float* wp = wk + t * 32;          // wave-uniform -> s_load
                    #pragma unroll
                    for (int oc = 0; oc < 32; oc++) acc[oc] = fmaf(pix, wp[oc], acc[oc]);
                }
            }
            uint_t* op = (uint_t*)(c1g + ((size_t)n * 400 + px) * 32);
            #pragma unroll
            for (int oc = 0; oc < 32; oc += 2)
                op[oc >> 1] = pack2(relu_f(acc[oc]), relu_f(acc[oc + 1]));
        }
    }
}

// ---------------- fused conv2+conv3: c1 -> (LDS) -> c2 -> (LDS) -> out3[n][3136] bf16 ----------------
// conv2: 20x20x32 -> 9x9x64 (k4 s2); conv3: 9x9x64 -> 7x7x64 (k3 s1)
__global__ __launch_bounds__(256) void conv23_kernel(
    const ushort_t* __restrict__ c1g,
    const float* __restrict__ W2, const float* __restrict__ b2,
    const float* __restrict__ W3, const float* __restrict__ b3,
    ushort_t* __restrict__ out3)
{
    __shared__ ushort_t c1_s[400 * 34];   // stride 34 elems (17 dwords) - breaks 32-elem bank stride
    __shared__ ushort_t c2_s[81 * 66];    // stride 66 elems (33 dwords) - conflict-free
    int n = blockIdx.x, tid = threadIdx.x;

    // stage c1 (coalesced dwords, repack to padded stride)
    const uint_t* gp = (const uint_t*)(c1g + (size_t)n * 12800);
    uint_t* l1 = (uint_t*)c1_s;
    for (int g = tid; g < 6400; g += 256) { int px = g >> 4, c = g & 15; l1[px * 17 + c] = gp[g]; }
    __syncthreads();

    // conv2: space 512 = 4 oc-quarters x 128 px-slots (px<81); q wave-uniform
    for (int pass = 0; pass < 2; pass++) {
        int idx = pass * 256 + tid;
        int q = (idx >> 7) & 3, px = idx & 127;
        int oc0 = __builtin_amdgcn_readfirstlane(q * 16);
        if (px < 81) {
            int oy = px / 9, ox = px % 9;
            float acc[16];
            #pragma unroll
            for (int j = 0; j < 16; j++) acc[j] = b2[oc0 + j];
            for (int ky = 0; ky < 4; ky++) {
                for (int kx = 0; kx < 4; kx++) {
                    const ushort_t* crow = c1_s + ((oy * 2 + ky) * 20 + ox * 2 + kx) * 34;
                    const float* wk = W2 + ((ky * 4 + kx) * 32) * 64 + oc0;   // wave-uniform
                    #pragma unroll
                    for (int ic = 0; ic < 32; ic++) {
                        float pix = bf2f(crow[ic]);
                        const float* wp = wk + ic * 64;
                        #pragma unroll
                        for (int j = 0; j < 16; j++) acc[j] = fmaf(pix, wp[j], acc[j]);
                    }
                }
            }
            ushort_t* orow = c2_s + px * 66 + oc0;
            #pragma unroll
            for (int j = 0; j < 16; j++) orow[j] = f2bf(relu_f(acc[j]));
        }
    }
    __syncthreads();

    // conv3: space 256 = 4 oc-quarters x 64 px-slots (px<49); q wave-uniform
    {
        int q = tid >> 6, px = tid & 63;
        int oc0 = __builtin_amdgcn_readfirstlane(q * 16);
        if (px < 49) {
            int oy = px / 7, ox = px % 7;
            float acc[16];
            #pragma unroll
            for (int j = 0; j < 16; j++) acc[j] = b3[oc0 + j];
            for (int ky = 0; ky < 3; ky++) {
                for (int kx = 0; kx < 3; kx++) {
                    const ushort_t* crow = c2_s + ((oy + ky) * 9 + ox + kx) * 66;
                    const float* wk = W3 + ((ky * 3 + kx) * 64) * 64 + oc0;   // wave-uniform
                    #pragma unroll
                    for (int ic = 0; ic < 64; ic++) {
                        float pix = bf2f(crow[ic]);
                        const float* wp = wk + ic * 64;
                        #pragma unroll
                        for (int j = 0; j < 16; j++) acc[j] = fmaf(pix, wp[j], acc[j]);
                    }
                }
            }
            uint_t* op = (uint_t*)(out3 + (size_t)n * 3136 + px * 64 + oc0);
            #pragma unroll
            for (int j = 0; j < 16; j += 2)
                op[j >> 1] = pack2(relu_f(acc[j]), relu_f(acc[j + 1]));
        }
    }
}

// ---------------- transpose: out3[n][3136] -> out3T[k][n], 64x64 LDS tiles ----------------
__global__ __launch_bounds__(256) void transpose_kernel(
    const ushort_t* __restrict__ in, ushort_t* __restrict__ out)
{
    __shared__ ushort_t t_s[64][65];
    int kb = blockIdx.x % 49, nb = blockIdx.x / 49;   // 49*32 blocks
    int k0 = kb * 64, n0 = nb * 64;
    int j = threadIdx.x & 63, i4 = threadIdx.x >> 6;
    for (int r = i4; r < 64; r += 4)
        t_s[r][j] = in[(size_t)(n0 + r) * 3136 + k0 + j];
    __syncthreads();
    for (int r = i4; r < 64; r += 4)
        out[(size_t)(k0 + r) * NT + n0 + j] = t_s[j][r];
}

// ---------------- FC: feat = relu(out3 @ Wfc + bfc); reads out3T[k][n] -> featT[j][n] ----------------
__global__ __launch_bounds__(256) void fc_kernel(
    const ushort_t* __restrict__ A,      // [3136][2048]
    const float* __restrict__ Wfc, const float* __restrict__ bfc,
    ushort_t* __restrict__ featT)        // [512][2048]
{
    int bid = blockIdx.x;                // 512 = 8 n-blocks x 64 j-groups
    int jg = bid & 63, nb = bid >> 6;
    int n = nb * 256 + threadIdx.x;
    int j0 = jg * 8;
    float acc[8];
    #pragma unroll
    for (int j = 0; j < 8; j++) acc[j] = bfc[j0 + j];
    for (int k = 0; k < 3136; k++) {
        float a = bf2f(A[(size_t)k * NT + n]);
        const float* wp = Wfc + (size_t)k * 512 + j0;
        #pragma unroll
        for (int j = 0; j < 8; j++) acc[j] = fmaf(a, wp[j], acc[j]);
    }
    #pragma unroll
    for (int j = 0; j < 8; j++)
        featT[(size_t)(j0 + j) * NT + n] = f2bf(relu_f(acc[j]));
}

// ---------------- gates_x: gx[n][512] = feat @ WihT + onehot rows + bias row (fp32) ----------------
__global__ __launch_bounds__(256) void gates_kernel(
    const ushort_t* __restrict__ featT, const float* __restrict__ WihTc,
    const int* __restrict__ pos, float* __restrict__ gx)
{
    int bid = blockIdx.x;                // 512 = 8 n-blocks x 64 j-groups
    int jg = bid & 63, nb = bid >> 6;
    int n = nb * 256 + threadIdx.x;
    int j0 = jg * 8;
    float acc[8];
    const float* bias = WihTc + 532 * 512 + j0;
    int p0 = pos[2 * n], p1 = pos[2 * n + 1];
    const float* r0 = WihTc + (size_t)(512 + p0) * 512 + j0;
    const float* r1 = WihTc + (size_t)(522 + p1) * 512 + j0;
    #pragma unroll
    for (int j = 0; j < 8; j++) acc[j] = bias[j] + r0[j] + r1[j];
    for (int k = 0; k < 512; k++) {
        float a = bf2f(featT[(size_t)k * NT + n]);
        const float* wp = WihTc + (size_t)k * 512 + j0;
        #pragma unroll
        for (int j = 0; j < 8; j++) acc[j] = fmaf(a, wp[j], acc[j]);
    }
    float* o = gx + (size_t)n * 512 + j0;
    #pragma unroll
    for (int j = 0; j < 8; j++) o[j] = acc[j];
}

// ---------------- LSTM: 32 independent blocks (one per batch element), no grid barrier ----------------
// thread = (gate g = tid>>7, hid j = tid&127); Whh row held in 128 VGPRs
__global__ __launch_bounds__(512, 2) void lstm_kernel(
    const float* __restrict__ gx, const float* __restrict__ Whh,
    const int* __restrict__ done, const float* __restrict__ h0,
    const float* __restrict__ c0, ushort_t* __restrict__ hs,
    float* __restrict__ out)
{
    __shared__ __align__(16) float h_s[128];
    __shared__ float gates_s[512];
    int b = blockIdx.x, tid = threadIdx.x;
    int g = tid >> 7, j = tid & 127;

    float w[128];
    const float* wr = Whh + (size_t)(g * 128 + j) * 128;
    #pragma unroll
    for (int k = 0; k < 128; k += 4) {
        float4 v = *(const float4*)(wr + k);
        w[k] = v.x; w[k + 1] = v.y; w[k + 2] = v.z; w[k + 3] = v.w;
    }
    float h = h0[b * 128 + j];
    float c = c0[b * 128 + j];
    const float* gxb = gx + (size_t)b * 512;

    for (int t = 0; t < TT; t++) {
        float m = 1.0f - (float)done[t * 32 + b];
        c *= m;
        if (g == 0) h_s[j] = h * m;
        __syncthreads();
        float acc = 0.0f;
        #pragma unroll
        for (int k = 0; k < 128; k += 4) {
            float4 hv = *(const float4*)&h_s[k];
            acc = fmaf(w[k], hv.x, acc);
            acc = fmaf(w[k + 1], hv.y, acc);
            acc = fmaf(w[k + 2], hv.z, acc);
            acc = fmaf(w[k + 3], hv.w, acc);
        }
        acc += gxb[(size_t)t * 32 * 512 + (g << 7) + j];
        gates_s[(g << 7) + j] = acc;
        __syncthreads();
        float iv = sigmoid_f(gates_s[j]);
        float fv = sigmoid_f(gates_s[128 + j]);
        float gv = tanhf(gates_s[256 + j]);
        float ov = sigmoid_f(gates_s[384 + j]);
        c = fv * c + iv * gv;
        h = ov * tanhf(c);
        if (g == 0) hs[((size_t)t * 32 + b) * 128 + j] = f2bf(h);
    }
    if (g == 0) {
        out[12288 + b * 128 + j] = h;
        out[16384 + b * 128 + j] = c;
    }
}

// ---------------- heads: logits (2048x5), v (2048) ----------------
__global__ __launch_bounds__(256) void heads_kernel(
    const ushort_t* __restrict__ hs, const float* __restrict__ Wp,
    const float* __restrict__ bp, const float* __restrict__ Wv,
    const float* __restrict__ bv, float* __restrict__ out)
{
    int id = blockIdx.x * 256 + threadIdx.x;   // 12288 = 2048*6
    int n = id / 6, q = id % 6;
    const ushort_t* hrow = hs + (size_t)n * 128;
    if (q < 5) {
        float acc = bp[q];
        for (int k = 0; k < 128; k++) acc = fmaf(bf2f(hrow[k]), Wp[k * 5 + q], acc);
        out[n * 5 + q] = acc;
    } else {
        float acc = bv[0];
        for (int k = 0; k < 128; k++) acc = fmaf(bf2f(hrow[k]), Wv[k], acc);
        out[10240 + n] = acc;
    }
}

extern "C" void kernel_launch(void* const* d_in, const int* in_sizes, int n_in,
                              void* d_out, int out_size, void* d_ws, size_t ws_size,
                              hipStream_t stream) {
    const float* image = (const float*)d_in[0];
    const int*   pos   = (const int*)d_in[1];
    const int*   done  = (const int*)d_in[2];
    const float* h0    = (const float*)d_in[3];
    const float* c0    = (const float*)d_in[4];
    const float* W1    = (const float*)d_in[5];
    const float* b1    = (const float*)d_in[6];
    const float* W2    = (const float*)d_in[7];
    const float* b2    = (const float*)d_in[8];
    const float* W3    = (const float*)d_in[9];
    const float* b3    = (const float*)d_in[10];
    const float* Wfc   = (const float*)d_in[11];
    const float* bfc   = (const float*)d_in[12];
    const float* Wih   = (const float*)d_in[13];
    const float* Whh   = (const float*)d_in[14];
    const float* bih   = (const float*)d_in[15];
    const float* bhh   = (const float*)d_in[16];
    const float* Wp    = (const float*)d_in[17];
    const float* bp    = (const float*)d_in[18];
    const float* Wv    = (const float*)d_in[19];
    const float* bv    = (const float*)d_in[20];

    char* ws = (char*)d_ws;
    float*    WihTc = (float*)(ws + 0);             // 1,091,584 B
    ushort_t* c1g   = (ushort_t*)(ws + 1091584);    // 26,214,400 B (half-batch) -> ends 27,305,984
    ushort_t* featT = (ushort_t*)(ws + 1091584);    // 2,097,152 B — reuses c1g region (dead after conv23)
    ushort_t* out3  = (ushort_t*)(ws + 27305984);   // 12,845,056 B -> ends 40,151,040
    ushort_t* out3T = (ushort_t*)(ws + 40151040);   // 12,845,056 B -> ends 52,996,096
    float*    gx    = (float*)(ws + 52996096);      // 4,194,304 B  -> ends 57,190,400
    ushort_t* hs    = (ushort_t*)(ws + 57190400);   // 524,288 B    -> ends 57,714,688

    float* out = (float*)d_out;

    prep_kernel<<<1066, 256, 0, stream>>>(Wih, bih, bhh, WihTc);
    // conv pipeline in two n-halves to cap workspace (c1g reused)
    for (int half = 0; half < 2; half++) {
        const float* imgh = image + (size_t)half * 1024 * 21168;
        ushort_t* out3h = out3 + (size_t)half * 1024 * 3136;
        conv1_kernel<<<1024, 256, 0, stream>>>(imgh, W1, b1, c1g);
        conv23_kernel<<<1024, 256, 0, stream>>>(c1g, W2, b2, W3, b3, out3h);
    }
    transpose_kernel<<<1568, 256, 0, stream>>>(out3, out3T);
    fc_kernel<<<512, 256, 0, stream>>>(out3T, Wfc, bfc, featT);
    gates_kernel<<<512, 256, 0, stream>>>(featT, WihTc, pos, gx);
    lstm_kernel<<<32, 512, 0, stream>>>(gx, Whh, done, h0, c0, hs, out);
    heads_kernel<<<48, 256, 0, stream>>>(hs, Wp, bp, Wv, bv, out);
}

// Round 4
// 948.467 us; speedup vs baseline: 3.8694x; 1.2824x over previous
//
#include <hip/hip_runtime.h>

typedef unsigned short ushort_t;
typedef unsigned int uint_t;
typedef __attribute__((ext_vector_type(8))) short short8;
typedef __attribute__((ext_vector_type(4))) float floatx4;

__device__ __forceinline__ float bf2f(ushort_t u){
    union { uint_t i; float f; } c; c.i = ((uint_t)u) << 16; return c.f;
}
__device__ __forceinline__ ushort_t f2bf(float x){
    union { float f; uint_t i; } c; c.f = x;
    uint_t i = c.i;
    return (ushort_t)((i + 0x7fffu + ((i >> 16) & 1u)) >> 16);
}
__device__ __forceinline__ uint_t pack2(float a, float b){
    return (uint_t)f2bf(a) | ((uint_t)f2bf(b) << 16);
}
__device__ __forceinline__ float relu_f(float x){ return fmaxf(x, 0.0f); }
__device__ __forceinline__ float sigmoid_f(float x){ return 1.0f / (1.0f + __expf(-x)); }

#define NT 2048
#define TT 64

// ---------------- prep: Wihb[j][k] = bf16(Wih[j][k]), k<512 ----------------
__global__ __launch_bounds__(256) void prep_kernel(
    const float* __restrict__ Wih, ushort_t* __restrict__ Wihb)
{
    int i = blockIdx.x * 256 + threadIdx.x;   // 262144
    int j = i >> 9, k = i & 511;
    Wihb[i] = f2bf(Wih[j * 532 + k]);
}

// ---------------- wfct: Wfc[3136][512] f32 -> WfcT[512][3136] bf16 ----------------
__global__ __launch_bounds__(256) void wfct_kernel(
    const float* __restrict__ Wfc, ushort_t* __restrict__ WfcT)
{
    __shared__ ushort_t t_s[64][65];
    int kb = blockIdx.x % 49, jb = blockIdx.x / 49;   // 49*8 blocks
    int k0 = kb * 64, j0 = jb * 64;
    int jj = threadIdx.x & 63, i4 = threadIdx.x >> 6;
    for (int rr = i4; rr < 64; rr += 4)
        t_s[rr][jj] = f2bf(Wfc[(size_t)(k0 + rr) * 512 + j0 + jj]);
    __syncthreads();
    for (int rr = i4; rr < 64; rr += 4)
        WfcT[(size_t)(j0 + rr) * 3136 + k0 + jj] = t_s[jj][rr];
}

// ---------------- conv1: 84x84x3 -> 20x20x32, k=8 s=4 ; image staged in LDS bf16 ----------------
__global__ __launch_bounds__(256) void conv1_kernel(
    const float* __restrict__ img, const float* __restrict__ W1,
    const float* __restrict__ b1, ushort_t* __restrict__ c1g)
{
    __shared__ ushort_t img_s[21168];   // 42336 B -> 3 blocks/CU
    int n = blockIdx.x, tid = threadIdx.x;
    const float2* ip = (const float2*)(img + (size_t)n * 21168);
    uint_t* ls = (uint_t*)img_s;
    for (int i = tid; i < 10584; i += 256) { float2 v = ip[i]; ls[i] = pack2(v.x, v.y); }
    __syncthreads();

    for (int pass = 0; pass < 2; pass++) {
        int px = pass * 256 + tid;
        if (px < 400) {
            int oy = px / 20, ox = px % 20;
            float acc[32];
            #pragma unroll
            for (int oc = 0; oc < 32; oc++) acc[oc] = b1[oc];
            for (int ky = 0; ky < 8; ky++) {
                int base = ((oy * 4 + ky) * 84 + ox * 4) * 3;
                const float* wk = W1 + ky * 768;
                #pragma unroll
                for (int t = 0; t < 24; t++) {
                    float pix = bf2f(img_s[base + t]);
                    const float* wp = wk + t * 32;          // wave-uniform -> s_load
                    #pragma unroll
                    for (int oc = 0; oc < 32; oc++) acc[oc] = fmaf(pix, wp[oc], acc[oc]);
                }
            }
            uint_t* op = (uint_t*)(c1g + ((size_t)n * 400 + px) * 32);
            #pragma unroll
            for (int oc = 0; oc < 32; oc += 2)
                op[oc >> 1] = pack2(relu_f(acc[oc]), relu_f(acc[oc + 1]));
        }
    }
}

// ---------------- fused conv2+conv3: c1 -> (LDS) -> c2 -> (LDS) -> out3[n][3136] bf16 ----------------
__global__ __launch_bounds__(256) void conv23_kernel(
    const ushort_t* __restrict__ c1g,
    const float* __restrict__ W2, const float* __restrict__ b2,
    const float* __restrict__ W3, const float* __restrict__ b3,
    ushort_t* __restrict__ out3)
{
    __shared__ ushort_t c1_s[400 * 34];   // stride 34 elems
    __shared__ ushort_t c2_s[81 * 66];    // stride 66 elems
    int n = blockIdx.x, tid = threadIdx.x;

    const uint_t* gp = (const uint_t*)(c1g + (size_t)n * 12800);
    uint_t* l1 = (uint_t*)c1_s;
    for (int g = tid; g < 6400; g += 256) { int px = g >> 4, c = g & 15; l1[px * 17 + c] = gp[g]; }
    __syncthreads();

    for (int pass = 0; pass < 2; pass++) {
        int idx = pass * 256 + tid;
        int q = (idx >> 7) & 3, px = idx & 127;
        int oc0 = __builtin_amdgcn_readfirstlane(q * 16);
        if (px < 81) {
            int oy = px / 9, ox = px % 9;
            float acc[16];
            #pragma unroll
            for (int j = 0; j < 16; j++) acc[j] = b2[oc0 + j];
            for (int ky = 0; ky < 4; ky++) {
                for (int kx = 0; kx < 4; kx++) {
                    const ushort_t* crow = c1_s + ((oy * 2 + ky) * 20 + ox * 2 + kx) * 34;
                    const float* wk = W2 + ((ky * 4 + kx) * 32) * 64 + oc0;
                    #pragma unroll
                    for (int ic = 0; ic < 32; ic++) {
                        float pix = bf2f(crow[ic]);
                        const float* wp = wk + ic * 64;
                        #pragma unroll
                        for (int j = 0; j < 16; j++) acc[j] = fmaf(pix, wp[j], acc[j]);
                    }
                }
            }
            ushort_t* orow = c2_s + px * 66 + oc0;
            #pragma unroll
            for (int j = 0; j < 16; j++) orow[j] = f2bf(relu_f(acc[j]));
        }
    }
    __syncthreads();

    {
        int q = tid >> 6, px = tid & 63;
        int oc0 = __builtin_amdgcn_readfirstlane(q * 16);
        if (px < 49) {
            int oy = px / 7, ox = px % 7;
            float acc[16];
            #pragma unroll
            for (int j = 0; j < 16; j++) acc[j] = b3[oc0 + j];
            for (int ky = 0; ky < 3; ky++) {
                for (int kx = 0; kx < 3; kx++) {
                    const ushort_t* crow = c2_s + ((oy + ky) * 9 + ox + kx) * 66;
                    const float* wk = W3 + ((ky * 3 + kx) * 64) * 64 + oc0;
                    #pragma unroll
                    for (int ic = 0; ic < 64; ic++) {
                        float pix = bf2f(crow[ic]);
                        const float* wp = wk + ic * 64;
                        #pragma unroll
                        for (int j = 0; j < 16; j++) acc[j] = fmaf(pix, wp[j], acc[j]);
                    }
                }
            }
            uint_t* op = (uint_t*)(out3 + (size_t)n * 3136 + px * 64 + oc0);
            #pragma unroll
            for (int j = 0; j < 16; j += 2)
                op[j >> 1] = pack2(relu_f(acc[j]), relu_f(acc[j + 1]));
        }
    }
}

// ---------------- FC via MFMA: feat[2048][512] = relu(out3 @ Wfc + bfc) ----------------
// A = out3[n][3136] bf16, B^T = WfcT[512][3136] bf16. Tile M=32 x N=64, 4 waves.
__global__ __launch_bounds__(256) void fc_mfma_kernel(
    const ushort_t* __restrict__ A, const ushort_t* __restrict__ BT,
    const float* __restrict__ bfc, ushort_t* __restrict__ feat)
{
    int mb = blockIdx.x & 63, nb = blockIdx.x >> 6;   // 64 x 8
    int tid = threadIdx.x;
    int w = tid >> 6, lane = tid & 63;
    int r = lane & 15, q = lane >> 4;
    int m0 = mb * 32 + (w & 1) * 16;
    int n0 = nb * 64 + (w >> 1) * 32;
    const ushort_t* arow  = A  + (size_t)(m0 + r) * 3136 + q * 8;
    const ushort_t* brow0 = BT + (size_t)(n0 + r) * 3136 + q * 8;
    const ushort_t* brow1 = BT + (size_t)(n0 + 16 + r) * 3136 + q * 8;
    floatx4 acc0 = {0.f, 0.f, 0.f, 0.f}, acc1 = {0.f, 0.f, 0.f, 0.f};
    short8 a  = *(const short8*)arow;
    short8 b0 = *(const short8*)brow0;
    short8 b1 = *(const short8*)brow1;
    for (int kk = 1; kk < 98; kk++) {
        short8 an  = *(const short8*)(arow  + kk * 32);
        short8 b0n = *(const short8*)(brow0 + kk * 32);
        short8 b1n = *(const short8*)(brow1 + kk * 32);
        acc0 = __builtin_amdgcn_mfma_f32_16x16x32_bf16(a, b0, acc0, 0, 0, 0);
        acc1 = __builtin_amdgcn_mfma_f32_16x16x32_bf16(a, b1, acc1, 0, 0, 0);
        a = an; b0 = b0n; b1 = b1n;
    }
    acc0 = __builtin_amdgcn_mfma_f32_16x16x32_bf16(a, b0, acc0, 0, 0, 0);
    acc1 = __builtin_amdgcn_mfma_f32_16x16x32_bf16(a, b1, acc1, 0, 0, 0);
    int c0 = n0 + r, c1 = n0 + 16 + r;
    float bb0 = bfc[c0], bb1 = bfc[c1];
    #pragma unroll
    for (int i = 0; i < 4; i++) {
        int row = m0 + q * 4 + i;
        feat[(size_t)row * 512 + c0] = f2bf(relu_f(acc0[i] + bb0));
        feat[(size_t)row * 512 + c1] = f2bf(relu_f(acc1[i] + bb1));
    }
}

// ---------------- gates via MFMA: gx[2048][512] = feat @ Wih[:,:512]^T + onehot + bias ----------------
__global__ __launch_bounds__(256) void gates_mfma_kernel(
    const ushort_t* __restrict__ A,      // feat [2048][512]
    const ushort_t* __restrict__ Wihb,   // [512][512] bf16 (j rows, k cols)
    const float* __restrict__ Wih, const float* __restrict__ bih,
    const float* __restrict__ bhh, const int* __restrict__ pos,
    float* __restrict__ gx)
{
    int mb = blockIdx.x & 63, nb = blockIdx.x >> 6;   // 64 x 8
    int tid = threadIdx.x;
    int w = tid >> 6, lane = tid & 63;
    int r = lane & 15, q = lane >> 4;
    int m0 = mb * 32 + (w & 1) * 16;
    int n0 = nb * 64 + (w >> 1) * 32;
    const ushort_t* arow  = A    + (size_t)(m0 + r) * 512 + q * 8;
    const ushort_t* brow0 = Wihb + (size_t)(n0 + r) * 512 + q * 8;
    const ushort_t* brow1 = Wihb + (size_t)(n0 + 16 + r) * 512 + q * 8;
    floatx4 acc0 = {0.f, 0.f, 0.f, 0.f}, acc1 = {0.f, 0.f, 0.f, 0.f};
    short8 a  = *(const short8*)arow;
    short8 b0 = *(const short8*)brow0;
    short8 b1 = *(const short8*)brow1;
    for (int kk = 1; kk < 16; kk++) {
        short8 an  = *(const short8*)(arow  + kk * 32);
        short8 b0n = *(const short8*)(brow0 + kk * 32);
        short8 b1n = *(const short8*)(brow1 + kk * 32);
        acc0 = __builtin_amdgcn_mfma_f32_16x16x32_bf16(a, b0, acc0, 0, 0, 0);
        acc1 = __builtin_amdgcn_mfma_f32_16x16x32_bf16(a, b1, acc1, 0, 0, 0);
        a = an; b0 = b0n; b1 = b1n;
    }
    acc0 = __builtin_amdgcn_mfma_f32_16x16x32_bf16(a, b0, acc0, 0, 0, 0);
    acc1 = __builtin_amdgcn_mfma_f32_16x16x32_bf16(a, b1, acc1, 0, 0, 0);
    int j0 = n0 + r, j1 = n0 + 16 + r;
    float bias0 = bih[j0] + bhh[j0];
    float bias1 = bih[j1] + bhh[j1];
    #pragma unroll
    for (int i = 0; i < 4; i++) {
        int row = m0 + q * 4 + i;
        int p0 = pos[2 * row], p1 = pos[2 * row + 1];
        float oh0 = Wih[(size_t)j0 * 532 + 512 + p0] + Wih[(size_t)j0 * 532 + 522 + p1];
        float oh1 = Wih[(size_t)j1 * 532 + 512 + p0] + Wih[(size_t)j1 * 532 + 522 + p1];
        gx[(size_t)row * 512 + j0] = acc0[i] + bias0 + oh0;
        gx[(size_t)row * 512 + j1] = acc1[i] + bias1 + oh1;
    }
}

// ---------------- LSTM: 32 independent blocks (one per batch element) ----------------
__global__ __launch_bounds__(512, 2) void lstm_kernel(
    const float* __restrict__ gx, const float* __restrict__ Whh,
    const int* __restrict__ done, const float* __restrict__ h0,
    const float* __restrict__ c0, ushort_t* __restrict__ hs,
    float* __restrict__ out)
{
    __shared__ __align__(16) float h_s[128];
    __shared__ float gates_s[512];
    int b = blockIdx.x, tid = threadIdx.x;
    int g = tid >> 7, j = tid & 127;

    float w[128];
    const float* wr = Whh + (size_t)(g * 128 + j) * 128;
    #pragma unroll
    for (int k = 0; k < 128; k += 4) {
        float4 v = *(const float4*)(wr + k);
        w[k] = v.x; w[k + 1] = v.y; w[k + 2] = v.z; w[k + 3] = v.w;
    }
    float h = h0[b * 128 + j];
    float c = c0[b * 128 + j];
    const float* gxb = gx + (size_t)b * 512;

    for (int t = 0; t < TT; t++) {
        float m = 1.0f - (float)done[t * 32 + b];
        c *= m;
        if (g == 0) h_s[j] = h * m;
        __syncthreads();
        float acc = 0.0f;
        #pragma unroll
        for (int k = 0; k < 128; k += 4) {
            float4 hv = *(const float4*)&h_s[k];
            acc = fmaf(w[k], hv.x, acc);
            acc = fmaf(w[k + 1], hv.y, acc);
            acc = fmaf(w[k + 2], hv.z, acc);
            acc = fmaf(w[k + 3], hv.w, acc);
        }
        acc += gxb[(size_t)t * 32 * 512 + (g << 7) + j];
        gates_s[(g << 7) + j] = acc;
        __syncthreads();
        float iv = sigmoid_f(gates_s[j]);
        float fv = sigmoid_f(gates_s[128 + j]);
        float gv = tanhf(gates_s[256 + j]);
        float ov = sigmoid_f(gates_s[384 + j]);
        c = fv * c + iv * gv;
        h = ov * tanhf(c);
        if (g == 0) hs[((size_t)t * 32 + b) * 128 + j] = f2bf(h);
    }
    if (g == 0) {
        out[12288 + b * 128 + j] = h;
        out[16384 + b * 128 + j] = c;
    }
}

// ---------------- heads: logits (2048x5), v (2048) ----------------
__global__ __launch_bounds__(256) void heads_kernel(
    const ushort_t* __restrict__ hs, const float* __restrict__ Wp,
    const float* __restrict__ bp, const float* __restrict__ Wv,
    const float* __restrict__ bv, float* __restrict__ out)
{
    int id = blockIdx.x * 256 + threadIdx.x;   // 12288 = 2048*6
    int n = id / 6, q = id % 6;
    const ushort_t* hrow = hs + (size_t)n * 128;
    if (q < 5) {
        float acc = bp[q];
        for (int k = 0; k < 128; k++) acc = fmaf(bf2f(hrow[k]), Wp[k * 5 + q], acc);
        out[n * 5 + q] = acc;
    } else {
        float acc = bv[0];
        for (int k = 0; k < 128; k++) acc = fmaf(bf2f(hrow[k]), Wv[k], acc);
        out[10240 + n] = acc;
    }
}

extern "C" void kernel_launch(void* const* d_in, const int* in_sizes, int n_in,
                              void* d_out, int out_size, void* d_ws, size_t ws_size,
                              hipStream_t stream) {
    const float* image = (const float*)d_in[0];
    const int*   pos   = (const int*)d_in[1];
    const int*   done  = (const int*)d_in[2];
    const float* h0    = (const float*)d_in[3];
    const float* c0    = (const float*)d_in[4];
    const float* W1    = (const float*)d_in[5];
    const float* b1    = (const float*)d_in[6];
    const float* W2    = (const float*)d_in[7];
    const float* b2    = (const float*)d_in[8];
    const float* W3    = (const float*)d_in[9];
    const float* b3    = (const float*)d_in[10];
    const float* Wfc   = (const float*)d_in[11];
    const float* bfc   = (const float*)d_in[12];
    const float* Wih   = (const float*)d_in[13];
    const float* Whh   = (const float*)d_in[14];
    const float* bih   = (const float*)d_in[15];
    const float* bhh   = (const float*)d_in[16];
    const float* Wp    = (const float*)d_in[17];
    const float* bp    = (const float*)d_in[18];
    const float* Wv    = (const float*)d_in[19];
    const float* bv    = (const float*)d_in[20];

    char* ws = (char*)d_ws;
    ushort_t* Wihb = (ushort_t*)(ws + 0);           //    524,288 B
    ushort_t* WfcT = (ushort_t*)(ws + 524288);      //  3,211,264 B -> 3,735,552
    ushort_t* c1g  = (ushort_t*)(ws + 3735552);     // 26,214,400 B -> 29,949,952
    ushort_t* out3 = (ushort_t*)(ws + 29949952);    // 12,845,056 B -> 42,795,008
    ushort_t* feat = (ushort_t*)(ws + 42795008);    //  2,097,152 B -> 44,892,160
    float*    gx   = (float*)(ws + 44892160);       //  4,194,304 B -> 49,086,464
    ushort_t* hs   = (ushort_t*)(ws + 49086464);    //    524,288 B -> 49,610,752

    float* out = (float*)d_out;

    prep_kernel<<<1024, 256, 0, stream>>>(Wih, Wihb);
    wfct_kernel<<<392, 256, 0, stream>>>(Wfc, WfcT);
    for (int half = 0; half < 2; half++) {
        const float* imgh = image + (size_t)half * 1024 * 21168;
        ushort_t* out3h = out3 + (size_t)half * 1024 * 3136;
        conv1_kernel<<<1024, 256, 0, stream>>>(imgh, W1, b1, c1g);
        conv23_kernel<<<1024, 256, 0, stream>>>(c1g, W2, b2, W3, b3, out3h);
    }
    fc_mfma_kernel<<<512, 256, 0, stream>>>(out3, WfcT, bfc, feat);
    gates_mfma_kernel<<<512, 256, 0, stream>>>(feat, Wihb, Wih, bih, bhh, pos, gx);
    lstm_kernel<<<32, 512, 0, stream>>>(gx, Whh, done, h0, c0, hs, out);
    heads_kernel<<<48, 256, 0, stream>>>(hs, Wp, bp, Wv, bv, out);
}

// Round 5
// 796.929 us; speedup vs baseline: 4.6052x; 1.1902x over previous
//
#include <hip/hip_runtime.h>

typedef unsigned short ushort_t;
typedef unsigned int uint_t;
typedef __attribute__((ext_vector_type(8))) short short8;
typedef __attribute__((ext_vector_type(4))) float floatx4;

__device__ __forceinline__ float bf2f(ushort_t u){
    union { uint_t i; float f; } c; c.i = ((uint_t)u) << 16; return c.f;
}
__device__ __forceinline__ ushort_t f2bf(float x){
    union { float f; uint_t i; } c; c.f = x;
    uint_t i = c.i;
    return (ushort_t)((i + 0x7fffu + ((i >> 16) & 1u)) >> 16);
}
__device__ __forceinline__ uint_t pack2(float a, float b){
    return (uint_t)f2bf(a) | ((uint_t)f2bf(b) << 16);
}
// fast pack of 2 fp32 -> 2 bf16 (round-half-up): 2 adds + v_perm
__device__ __forceinline__ uint_t cvt2fast(float a, float b){
    union { float f; uint_t i; } ca, cb; ca.f = a; cb.f = b;
    uint_t ia = ca.i + 0x8000u, ib = cb.i + 0x8000u;
    return __builtin_amdgcn_perm(ib, ia, 0x07060302u);
}
__device__ __forceinline__ float relu_f(float x){ return fmaxf(x, 0.0f); }
__device__ __forceinline__ float sigmoid_f(float x){ return 1.0f / (1.0f + __expf(-x)); }

#define NT 2048
#define TT 64

// ---------------- prep: Wihb[j][k] = bf16(Wih[j][k]), k<512 ----------------
__global__ __launch_bounds__(256) void prep_kernel(
    const float* __restrict__ Wih, ushort_t* __restrict__ Wihb)
{
    int i = blockIdx.x * 256 + threadIdx.x;   // 262144
    int j = i >> 9, k = i & 511;
    Wihb[i] = f2bf(Wih[j * 532 + k]);
}

// ---------------- prep conv weights: W1b[8][32oc][32k], W2b[16][64oc][32ic], W3b[9][64oc][64ic] ----------------
__global__ __launch_bounds__(256) void prep_convw_kernel(
    const float* __restrict__ W1, const float* __restrict__ W2,
    const float* __restrict__ W3, ushort_t* __restrict__ W1b,
    ushort_t* __restrict__ W2b, ushort_t* __restrict__ W3b)
{
    int i = blockIdx.x * 256 + threadIdx.x;   // 77824 total
    if (i < 8192) {                           // W1b: k = kx*3+ic (24 real, pad 8 zeros)
        int ky = i >> 10, oc = (i >> 5) & 31, k = i & 31;
        float v = 0.0f;
        if (k < 24) { int kx = k / 3, ic = k % 3; v = W1[((ky * 8 + kx) * 3 + ic) * 32 + oc]; }
        W1b[i] = f2bf(v);
        return;
    }
    i -= 8192;
    if (i < 32768) {                          // W2b[kk][oc][ic]
        int kk = i >> 11, oc = (i >> 5) & 63, ic = i & 31;
        W2b[i] = f2bf(W2[(kk * 32 + ic) * 64 + oc]);
        return;
    }
    i -= 32768;
    if (i < 36864) {                          // W3b[p][oc][ic]
        int p = i >> 12, oc = (i >> 6) & 63, ic = i & 63;
        W3b[i] = f2bf(W3[(p * 64 + ic) * 64 + oc]);
    }
}

// ---------------- wfct: Wfc[3136][512] f32 -> WfcT[512][3136] bf16 ----------------
__global__ __launch_bounds__(256) void wfct_kernel(
    const float* __restrict__ Wfc, ushort_t* __restrict__ WfcT)
{
    __shared__ ushort_t t_s[64][65];
    int kb = blockIdx.x % 49, jb = blockIdx.x / 49;   // 49*8 blocks
    int k0 = kb * 64, j0 = jb * 64;
    int jj = threadIdx.x & 63, i4 = threadIdx.x >> 6;
    for (int rr = i4; rr < 64; rr += 4)
        t_s[rr][jj] = f2bf(Wfc[(size_t)(k0 + rr) * 512 + j0 + jj]);
    __syncthreads();
    for (int rr = i4; rr < 64; rr += 4)
        WfcT[(size_t)(j0 + rr) * 3136 + k0 + jj] = t_s[jj][rr];
}

// ---------------- conv1 via MFMA: 84x84x3 -> c1[n][400][32], k=8 s=4 ----------------
// implicit GEMM: m=16 samples, col=16 oc, K=32 (kx*3+ic, zero-padded); 8 ky MFMAs/px
__global__ __launch_bounds__(256) void conv1_mfma(
    const float* __restrict__ img, const ushort_t* __restrict__ W1b,
    const float* __restrict__ b1, ushort_t* __restrict__ c1)
{
    int bid = blockIdx.x;                // 512 = 128 ng x 4 pq
    int ng = bid >> 2, pq = bid & 3;
    int tid = threadIdx.x;
    int w = tid >> 6, lane = tid & 63;
    int oct = w & 1, ph = w >> 1;        // wave: oc-tile (2) x px-phase (2)
    int r = lane & 15, q = lane >> 4;
    int n0 = ng * 16;

    short8 bf[8];
    #pragma unroll
    for (int ky = 0; ky < 8; ky++)
        bf[ky] = *(const short8*)(W1b + ((ky * 32 + oct * 16 + r) * 32 + q * 8));
    const float* abase = img + (size_t)(n0 + r) * 21168;
    float bb = b1[oct * 16 + r];

    for (int px = pq * 2 + ph; px < 400; px += 8) {
        int oy = px / 20, ox = px % 20;
        floatx4 acc = {0.f, 0.f, 0.f, 0.f};
        #pragma unroll
        for (int ky = 0; ky < 8; ky++) {
            short8 a = {0,0,0,0,0,0,0,0};
            if (q < 3) {
                const float* p = abase + ((oy * 4 + ky) * 84 + ox * 4) * 3 + q * 8;
                float4 f0 = *(const float4*)p;
                float4 f1 = *(const float4*)(p + 4);
                uint_t u0 = cvt2fast(f0.x, f0.y);
                uint_t u1 = cvt2fast(f0.z, f0.w);
                uint_t u2 = cvt2fast(f1.x, f1.y);
                uint_t u3 = cvt2fast(f1.z, f1.w);
                union { uint_t u[4]; short8 s; } pk;
                pk.u[0] = u0; pk.u[1] = u1; pk.u[2] = u2; pk.u[3] = u3;
                a = pk.s;
            }
            acc = __builtin_amdgcn_mfma_f32_16x16x32_bf16(a, bf[ky], acc, 0, 0, 0);
        }
        #pragma unroll
        for (int i = 0; i < 4; i++)
            c1[((size_t)(n0 + q * 4 + i) * 400 + px) * 32 + oct * 16 + r] =
                f2bf(relu_f(acc[i] + bb));
    }
}

// ---------------- conv2 via MFMA: c1[n][400][32] -> c2[n][81][64], k=4 s=2 ----------------
// 16 (ky,kx) positions x K=32; wave = one of 4 oc-tiles
__global__ __launch_bounds__(256) void conv2_mfma(
    const ushort_t* __restrict__ c1, const ushort_t* __restrict__ W2b,
    const float* __restrict__ b2, ushort_t* __restrict__ c2)
{
    int bid = blockIdx.x;                // 512 = 128 ng x 4 pq
    int ng = bid >> 2, pq = bid & 3;
    int tid = threadIdx.x;
    int w = tid >> 6, lane = tid & 63;   // wave = oc-tile
    int r = lane & 15, q = lane >> 4;
    int n0 = ng * 16;

    short8 bfr[16];
    #pragma unroll
    for (int kk = 0; kk < 16; kk++)
        bfr[kk] = *(const short8*)(W2b + ((kk * 64 + w * 16 + r) * 32 + q * 8));
    const ushort_t* abase = c1 + (size_t)(n0 + r) * 400 * 32 + q * 8;
    float bb = b2[w * 16 + r];

    for (int px = pq; px < 81; px += 4) {
        int oy = px / 9, ox = px % 9;
        floatx4 acc = {0.f, 0.f, 0.f, 0.f};
        #pragma unroll
        for (int ky = 0; ky < 4; ky++) {
            #pragma unroll
            for (int kx = 0; kx < 4; kx++) {
                int qin = (oy * 2 + ky) * 20 + ox * 2 + kx;
                short8 a = *(const short8*)(abase + qin * 32);
                acc = __builtin_amdgcn_mfma_f32_16x16x32_bf16(a, bfr[ky * 4 + kx], acc, 0, 0, 0);
            }
        }
        #pragma unroll
        for (int i = 0; i < 4; i++)
            c2[((size_t)(n0 + q * 4 + i) * 81 + px) * 64 + w * 16 + r] =
                f2bf(relu_f(acc[i] + bb));
    }
}

// ---------------- conv3 via MFMA: c2[n][81][64] -> out3[n][3136], k=3 s=1 ----------------
// 9 positions x K=64 (2 chunks); wave = one of 4 oc-tiles
__global__ __launch_bounds__(256) void conv3_mfma(
    const ushort_t* __restrict__ c2, const ushort_t* __restrict__ W3b,
    const float* __restrict__ b3, ushort_t* __restrict__ out3)
{
    int bid = blockIdx.x;                // 512 = 128 ng x 4 pq
    int ng = bid >> 2, pq = bid & 3;
    int tid = threadIdx.x;
    int w = tid >> 6, lane = tid & 63;   // wave = oc-tile
    int r = lane & 15, q = lane >> 4;
    int n0 = ng * 16;

    short8 bfr[18];
    #pragma unroll
    for (int p = 0; p < 9; p++) {
        #pragma unroll
        for (int h = 0; h < 2; h++)
            bfr[p * 2 + h] = *(const short8*)(W3b + ((p * 64 + w * 16 + r) * 64 + h * 32 + q * 8));
    }
    const ushort_t* abase = c2 + (size_t)(n0 + r) * 81 * 64 + q * 8;
    float bb = b3[w * 16 + r];

    for (int px = pq; px < 49; px += 4) {
        int oy = px / 7, ox = px % 7;
        floatx4 acc = {0.f, 0.f, 0.f, 0.f};
        #pragma unroll
        for (int ky = 0; ky < 3; ky++) {
            #pragma unroll
            for (int kx = 0; kx < 3; kx++) {
                int qin = (oy + ky) * 9 + ox + kx;
                const ushort_t* ap = abase + qin * 64;
                short8 a0 = *(const short8*)ap;
                short8 a1 = *(const short8*)(ap + 32);
                acc = __builtin_amdgcn_mfma_f32_16x16x32_bf16(a0, bfr[(ky * 3 + kx) * 2],     acc, 0, 0, 0);
                acc = __builtin_amdgcn_mfma_f32_16x16x32_bf16(a1, bfr[(ky * 3 + kx) * 2 + 1], acc, 0, 0, 0);
            }
        }
        #pragma unroll
        for (int i = 0; i < 4; i++)
            out3[(size_t)(n0 + q * 4 + i) * 3136 + px * 64 + w * 16 + r] =
                f2bf(relu_f(acc[i] + bb));
    }
}

// ---------------- FC via MFMA: feat[2048][512] = relu(out3 @ Wfc + bfc) ----------------
__global__ __launch_bounds__(256) void fc_mfma_kernel(
    const ushort_t* __restrict__ A, const ushort_t* __restrict__ BT,
    const float* __restrict__ bfc, ushort_t* __restrict__ feat)
{
    int mb = blockIdx.x & 63, nb = blockIdx.x >> 6;   // 64 x 8
    int tid = threadIdx.x;
    int w = tid >> 6, lane = tid & 63;
    int r = lane & 15, q = lane >> 4;
    int m0 = mb * 32 + (w & 1) * 16;
    int n0 = nb * 64 + (w >> 1) * 32;
    const ushort_t* arow  = A  + (size_t)(m0 + r) * 3136 + q * 8;
    const ushort_t* brow0 = BT + (size_t)(n0 + r) * 3136 + q * 8;
    const ushort_t* brow1 = BT + (size_t)(n0 + 16 + r) * 3136 + q * 8;
    floatx4 acc0 = {0.f, 0.f, 0.f, 0.f}, acc1 = {0.f, 0.f, 0.f, 0.f};
    short8 a  = *(const short8*)arow;
    short8 b0 = *(const short8*)brow0;
    short8 b1 = *(const short8*)brow1;
    for (int kk = 1; kk < 98; kk++) {
        short8 an  = *(const short8*)(arow  + kk * 32);
        short8 b0n = *(const short8*)(brow0 + kk * 32);
        short8 b1n = *(const short8*)(brow1 + kk * 32);
        acc0 = __builtin_amdgcn_mfma_f32_16x16x32_bf16(a, b0, acc0, 0, 0, 0);
        acc1 = __builtin_amdgcn_mfma_f32_16x16x32_bf16(a, b1, acc1, 0, 0, 0);
        a = an; b0 = b0n; b1 = b1n;
    }
    acc0 = __builtin_amdgcn_mfma_f32_16x16x32_bf16(a, b0, acc0, 0, 0, 0);
    acc1 = __builtin_amdgcn_mfma_f32_16x16x32_bf16(a, b1, acc1, 0, 0, 0);
    int c0 = n0 + r, c1 = n0 + 16 + r;
    float bb0 = bfc[c0], bb1 = bfc[c1];
    #pragma unroll
    for (int i = 0; i < 4; i++) {
        int row = m0 + q * 4 + i;
        feat[(size_t)row * 512 + c0] = f2bf(relu_f(acc0[i] + bb0));
        feat[(size_t)row * 512 + c1] = f2bf(relu_f(acc1[i] + bb1));
    }
}

// ---------------- gates via MFMA: gx[2048][512] = feat @ Wih[:,:512]^T + onehot + bias ----------------
__global__ __launch_bounds__(256) void gates_mfma_kernel(
    const ushort_t* __restrict__ A, const ushort_t* __restrict__ Wihb,
    const float* __restrict__ Wih, const float* __restrict__ bih,
    const float* __restrict__ bhh, const int* __restrict__ pos,
    float* __restrict__ gx)
{
    int mb = blockIdx.x & 63, nb = blockIdx.x >> 6;   // 64 x 8
    int tid = threadIdx.x;
    int w = tid >> 6, lane = tid & 63;
    int r = lane & 15, q = lane >> 4;
    int m0 = mb * 32 + (w & 1) * 16;
    int n0 = nb * 64 + (w >> 1) * 32;
    const ushort_t* arow  = A    + (size_t)(m0 + r) * 512 + q * 8;
    const ushort_t* brow0 = Wihb + (size_t)(n0 + r) * 512 + q * 8;
    const ushort_t* brow1 = Wihb + (size_t)(n0 + 16 + r) * 512 + q * 8;
    floatx4 acc0 = {0.f, 0.f, 0.f, 0.f}, acc1 = {0.f, 0.f, 0.f, 0.f};
    short8 a  = *(const short8*)arow;
    short8 b0 = *(const short8*)brow0;
    short8 b1 = *(const short8*)brow1;
    for (int kk = 1; kk < 16; kk++) {
        short8 an  = *(const short8*)(arow  + kk * 32);
        short8 b0n = *(const short8*)(brow0 + kk * 32);
        short8 b1n = *(const short8*)(brow1 + kk * 32);
        acc0 = __builtin_amdgcn_mfma_f32_16x16x32_bf16(a, b0, acc0, 0, 0, 0);
        acc1 = __builtin_amdgcn_mfma_f32_16x16x32_bf16(a, b1, acc1, 0, 0, 0);
        a = an; b0 = b0n; b1 = b1n;
    }
    acc0 = __builtin_amdgcn_mfma_f32_16x16x32_bf16(a, b0, acc0, 0, 0, 0);
    acc1 = __builtin_amdgcn_mfma_f32_16x16x32_bf16(a, b1, acc1, 0, 0, 0);
    int j0 = n0 + r, j1 = n0 + 16 + r;
    float bias0 = bih[j0] + bhh[j0];
    float bias1 = bih[j1] + bhh[j1];
    #pragma unroll
    for (int i = 0; i < 4; i++) {
        int row = m0 + q * 4 + i;
        int p0 = pos[2 * row], p1 = pos[2 * row + 1];
        float oh0 = Wih[(size_t)j0 * 532 + 512 + p0] + Wih[(size_t)j0 * 532 + 522 + p1];
        float oh1 = Wih[(size_t)j1 * 532 + 512 + p0] + Wih[(size_t)j1 * 532 + 522 + p1];
        gx[(size_t)row * 512 + j0] = acc0[i] + bias0 + oh0;
        gx[(size_t)row * 512 + j1] = acc1[i] + bias1 + oh1;
    }
}

// ---------------- LSTM: 32 independent blocks (one per batch element) ----------------
__global__ __launch_bounds__(512, 2) void lstm_kernel(
    const float* __restrict__ gx, const float* __restrict__ Whh,
    const int* __restrict__ done, const float* __restrict__ h0,
    const float* __restrict__ c0, ushort_t* __restrict__ hs,
    float* __restrict__ out)
{
    __shared__ __align__(16) float h_s[128];
    __shared__ float gates_s[512];
    int b = blockIdx.x, tid = threadIdx.x;
    int g = tid >> 7, j = tid & 127;

    float w[128];
    const float* wr = Whh + (size_t)(g * 128 + j) * 128;
    #pragma unroll
    for (int k = 0; k < 128; k += 4) {
        float4 v = *(const float4*)(wr + k);
        w[k] = v.x; w[k + 1] = v.y; w[k + 2] = v.z; w[k + 3] = v.w;
    }
    float h = h0[b * 128 + j];
    float c = c0[b * 128 + j];
    const float* gxb = gx + (size_t)b * 512;

    for (int t = 0; t < TT; t++) {
        float m = 1.0f - (float)done[t * 32 + b];
        c *= m;
        if (g == 0) h_s[j] = h * m;
        __syncthreads();
        float acc = 0.0f;
        #pragma unroll
        for (int k = 0; k < 128; k += 4) {
            float4 hv = *(const float4*)&h_s[k];
            acc = fmaf(w[k], hv.x, acc);
            acc = fmaf(w[k + 1], hv.y, acc);
            acc = fmaf(w[k + 2], hv.z, acc);
            acc = fmaf(w[k + 3], hv.w, acc);
        }
        acc += gxb[(size_t)t * 32 * 512 + (g << 7) + j];
        gates_s[(g << 7) + j] = acc;
        __syncthreads();
        float iv = sigmoid_f(gates_s[j]);
        float fv = sigmoid_f(gates_s[128 + j]);
        float gv = tanhf(gates_s[256 + j]);
        float ov = sigmoid_f(gates_s[384 + j]);
        c = fv * c + iv * gv;
        h = ov * tanhf(c);
        if (g == 0) hs[((size_t)t * 32 + b) * 128 + j] = f2bf(h);
    }
    if (g == 0) {
        out[12288 + b * 128 + j] = h;
        out[16384 + b * 128 + j] = c;
    }
}

// ---------------- heads: logits (2048x5), v (2048) ----------------
__global__ __launch_bounds__(256) void heads_kernel(
    const ushort_t* __restrict__ hs, const float* __restrict__ Wp,
    const float* __restrict__ bp, const float* __restrict__ Wv,
    const float* __restrict__ bv, float* __restrict__ out)
{
    int id = blockIdx.x * 256 + threadIdx.x;   // 12288 = 2048*6
    int n = id / 6, q = id % 6;
    const ushort_t* hrow = hs + (size_t)n * 128;
    if (q < 5) {
        float acc = bp[q];
        for (int k = 0; k < 128; k++) acc = fmaf(bf2f(hrow[k]), Wp[k * 5 + q], acc);
        out[n * 5 + q] = acc;
    } else {
        float acc = bv[0];
        for (int k = 0; k < 128; k++) acc = fmaf(bf2f(hrow[k]), Wv[k], acc);
        out[10240 + n] = acc;
    }
}

extern "C" void kernel_launch(void* const* d_in, const int* in_sizes, int n_in,
                              void* d_out, int out_size, void* d_ws, size_t ws_size,
                              hipStream_t stream) {
    const float* image = (const float*)d_in[0];
    const int*   pos   = (const int*)d_in[1];
    const int*   done  = (const int*)d_in[2];
    const float* h0    = (const float*)d_in[3];
    const float* c0    = (const float*)d_in[4];
    const float* W1    = (const float*)d_in[5];
    const float* b1    = (const float*)d_in[6];
    const float* W2    = (const float*)d_in[7];
    const float* b2    = (const float*)d_in[8];
    const float* W3    = (const float*)d_in[9];
    const float* b3    = (const float*)d_in[10];
    const float* Wfc   = (const float*)d_in[11];
    const float* bfc   = (const float*)d_in[12];
    const float* Wih   = (const float*)d_in[13];
    const float* Whh   = (const float*)d_in[14];
    const float* bih   = (const float*)d_in[15];
    const float* bhh   = (const float*)d_in[16];
    const float* Wp    = (const float*)d_in[17];
    const float* bp    = (const float*)d_in[18];
    const float* Wv    = (const float*)d_in[19];
    const float* bv    = (const float*)d_in[20];

    char* ws = (char*)d_ws;
    // weights
    ushort_t* Wihb = (ushort_t*)(ws + 0);           //   524,288 B
    ushort_t* WfcT = (ushort_t*)(ws + 524288);      // 3,211,264 -> 3,735,552
    ushort_t* W1b  = (ushort_t*)(ws + 3735552);     //    16,384 -> 3,751,936
    ushort_t* W2b  = (ushort_t*)(ws + 3751936);     //    65,536 -> 3,817,472
    ushort_t* W3b  = (ushort_t*)(ws + 3817472);     //    73,728 -> 3,891,200
    // activations; c1 region [4,194,304 .. 56,623,104) is reused by
    // out3/feat/gx/hs (all written strictly after c1's last read in conv2)
    ushort_t* out3 = (ushort_t*)(ws + 4194304);     // 12,845,056 -> 17,039,360
    ushort_t* feat = (ushort_t*)(ws + 17039360);    //  2,097,152 -> 19,136,512
    float*    gx   = (float*)(ws + 19136512);       //  4,194,304 -> 23,330,816
    ushort_t* hs   = (ushort_t*)(ws + 23330816);    //    524,288 -> 23,855,104
    ushort_t* c1   = (ushort_t*)(ws + 4194304);     // 52,428,800 -> 56,623,104
    ushort_t* c2   = (ushort_t*)(ws + 56623104);    // 21,233,664 -> 77,856,768

    float* out = (float*)d_out;

    prep_kernel<<<1024, 256, 0, stream>>>(Wih, Wihb);
    prep_convw_kernel<<<304, 256, 0, stream>>>(W1, W2, W3, W1b, W2b, W3b);
    wfct_kernel<<<392, 256, 0, stream>>>(Wfc, WfcT);
    conv1_mfma<<<512, 256, 0, stream>>>(image, W1b, b1, c1);
    conv2_mfma<<<512, 256, 0, stream>>>(c1, W2b, b2, c2);
    conv3_mfma<<<512, 256, 0, stream>>>(c2, W3b, b3, out3);
    fc_mfma_kernel<<<512, 256, 0, stream>>>(out3, WfcT, bfc, feat);
    gates_mfma_kernel<<<512, 256, 0, stream>>>(feat, Wihb, Wih, bih, bhh, pos, gx);
    lstm_kernel<<<32, 512, 0, stream>>>(gx, Whh, done, h0, c0, hs, out);
    heads_kernel<<<48, 256, 0, stream>>>(hs, Wp, bp, Wv, bv, out);
}

// Round 6
// 539.073 us; speedup vs baseline: 6.8080x; 1.4783x over previous
//
#include <hip/hip_runtime.h>

typedef unsigned short ushort_t;
typedef unsigned int uint_t;
typedef __attribute__((ext_vector_type(8))) short short8;
typedef __attribute__((ext_vector_type(4))) short short4v;
typedef __attribute__((ext_vector_type(4))) float floatx4;

__device__ __forceinline__ float bf2f(ushort_t u){
    union { uint_t i; float f; } c; c.i = ((uint_t)u) << 16; return c.f;
}
__device__ __forceinline__ ushort_t f2bf(float x){
    union { float f; uint_t i; } c; c.f = x;
    uint_t i = c.i;
    return (ushort_t)((i + 0x7fffu + ((i >> 16) & 1u)) >> 16);
}
// fast pack of 2 fp32 -> 2 bf16 (round-half-up): 2 adds + v_perm
__device__ __forceinline__ uint_t cvt2fast(float a, float b){
    union { float f; uint_t i; } ca, cb; ca.f = a; cb.f = b;
    uint_t ia = ca.i + 0x8000u, ib = cb.i + 0x8000u;
    return __builtin_amdgcn_perm(ib, ia, 0x07060302u);
}
// 16B fragment from LDS with only 8B alignment guaranteed -> 2x ds_read_b64
__device__ __forceinline__ short8 lds_load8(const ushort_t* p){
    union { short4v h[2]; short8 s; } u;
    u.h[0] = *(const short4v*)p;
    u.h[1] = *(const short4v*)(p + 4);
    return u.s;
}
__device__ __forceinline__ float relu_f(float x){ return fmaxf(x, 0.0f); }
__device__ __forceinline__ float sigmoid_f(float x){ return 1.0f / (1.0f + __expf(-x)); }

#define NT 2048
#define TT 64

// ---------------- prep: Wihb[j][k] = bf16(Wih[j][k]), k<512 ----------------
__global__ __launch_bounds__(256) void prep_kernel(
    const float* __restrict__ Wih, ushort_t* __restrict__ Wihb)
{
    int i = blockIdx.x * 256 + threadIdx.x;   // 262144
    int j = i >> 9, k = i & 511;
    Wihb[i] = f2bf(Wih[j * 532 + k]);
}

// ---------------- prep conv weights: W1b[8][32oc][32k], W2b[16][64oc][32ic], W3b[9][64oc][64ic] ----------------
__global__ __launch_bounds__(256) void prep_convw_kernel(
    const float* __restrict__ W1, const float* __restrict__ W2,
    const float* __restrict__ W3, ushort_t* __restrict__ W1b,
    ushort_t* __restrict__ W2b, ushort_t* __restrict__ W3b)
{
    int i = blockIdx.x * 256 + threadIdx.x;   // 77824 total
    if (i < 8192) {                           // W1b: k = kx*3+ic (24 real, pad 8 zeros)
        int ky = i >> 10, oc = (i >> 5) & 31, k = i & 31;
        float v = 0.0f;
        if (k < 24) { int kx = k / 3, ic = k % 3; v = W1[((ky * 8 + kx) * 3 + ic) * 32 + oc]; }
        W1b[i] = f2bf(v);
        return;
    }
    i -= 8192;
    if (i < 32768) {                          // W2b[kk][oc][ic]
        int kk = i >> 11, oc = (i >> 5) & 63, ic = i & 31;
        W2b[i] = f2bf(W2[(kk * 32 + ic) * 64 + oc]);
        return;
    }
    i -= 32768;
    if (i < 36864) {                          // W3b[p][oc][ic]
        int p = i >> 12, oc = (i >> 6) & 63, ic = i & 63;
        W3b[i] = f2bf(W3[(p * 64 + ic) * 64 + oc]);
    }
}

// ---------------- wfct: Wfc[3136][512] f32 -> WfcT[512][3136] bf16 ----------------
__global__ __launch_bounds__(256) void wfct_kernel(
    const float* __restrict__ Wfc, ushort_t* __restrict__ WfcT)
{
    __shared__ ushort_t t_s[64][65];
    int kb = blockIdx.x % 49, jb = blockIdx.x / 49;   // 49*8 blocks
    int k0 = kb * 64, j0 = jb * 64;
    int jj = threadIdx.x & 63, i4 = threadIdx.x >> 6;
    for (int rr = i4; rr < 64; rr += 4)
        t_s[rr][jj] = f2bf(Wfc[(size_t)(k0 + rr) * 512 + j0 + jj]);
    __syncthreads();
    for (int rr = i4; rr < 64; rr += 4)
        WfcT[(size_t)(j0 + rr) * 3136 + k0 + jj] = t_s[jj][rr];
}

// ---------------- fused convs via MFMA, block per sample ----------------
// image (LDS bf16, read once coalesced) -> conv1 -> c1_s -> conv2 -> c2_s -> conv3 -> out3
// m = 16 output pixels, col = 16 ocs, K = kernel-pos input channels
__global__ __launch_bounds__(256) void convs_mfma(
    const float* __restrict__ img,
    const ushort_t* __restrict__ W1b, const float* __restrict__ b1,
    const ushort_t* __restrict__ W2b, const float* __restrict__ b2,
    const ushort_t* __restrict__ W3b, const float* __restrict__ b3,
    ushort_t* __restrict__ out3)
{
    // c1_s: 400 px * 36 (stride 36 hw = 72 B: 8B-aligned frags, bank-step 4/r)
    // img_s: 21168 + 8 pad; c2_s: 81 px * 68 reuses img region after conv1
    __shared__ ushort_t smem[35576];               // 71,152 B -> 2 blocks/CU
    ushort_t* c1_s  = smem;                        // [0, 14400)
    ushort_t* img_s = smem + 14400;                // [14400, 35576)
    ushort_t* c2_s  = smem + 14400;                // 5508 hw, reuse

    int n = blockIdx.x, tid = threadIdx.x;
    int w = tid >> 6, lane = tid & 63;
    int r = lane & 15, q = lane >> 4;

    // ---- stage image fp32 -> bf16 LDS (coalesced float4) ----
    const float4* ip = (const float4*)(img + (size_t)n * 21168);
    for (int i = tid; i < 5292; i += 256) {
        float4 v = ip[i];
        uint_t lo = cvt2fast(v.x, v.y);
        uint_t hi = cvt2fast(v.z, v.w);
        *(uint2*)(img_s + i * 4) = make_uint2(lo, hi);
    }
    if (tid < 8) img_s[21168 + tid] = 0;           // pad for q=3 over-read
    __syncthreads();

    // ---- conv1: 20x20x32, k=8 s=4; K=32 (kx*3+ic, zero-padded 24..31) ----
    {
        int oct = w & 1;                           // 2 oc-tiles x 2 px-phases
        short8 bf[8];
        #pragma unroll
        for (int ky = 0; ky < 8; ky++)
            bf[ky] = *(const short8*)(W1b + (ky * 32 + oct * 16 + r) * 32 + q * 8);
        float bb = b1[oct * 16 + r];
        for (int t = (w >> 1); t < 25; t += 2) {
            int pxa = t * 16 + r;
            int oy = pxa / 20, ox = pxa % 20;
            floatx4 acc = {0.f, 0.f, 0.f, 0.f};
            #pragma unroll
            for (int ky = 0; ky < 8; ky++) {
                short8 a = lds_load8(img_s + ((oy * 4 + ky) * 84 + ox * 4) * 3 + q * 8);
                acc = __builtin_amdgcn_mfma_f32_16x16x32_bf16(a, bf[ky], acc, 0, 0, 0);
            }
            int pxs = t * 16 + q * 4;
            #pragma unroll
            for (int i = 0; i < 4; i++)
                c1_s[(pxs + i) * 36 + oct * 16 + r] = f2bf(relu_f(acc[i] + bb));
        }
    }
    __syncthreads();

    // ---- conv2: 9x9x64, k=4 s=2; 16 pos x K=32 ----
    {
        int oct = w;                               // 4 oc-tiles
        short8 bfr[16];
        #pragma unroll
        for (int kk = 0; kk < 16; kk++)
            bfr[kk] = *(const short8*)(W2b + (kk * 64 + oct * 16 + r) * 32 + q * 8);
        float bb = b2[oct * 16 + r];
        for (int t = 0; t < 6; t++) {
            int pxa = min(t * 16 + r, 80);
            int oy = pxa / 9, ox = pxa % 9;
            floatx4 acc = {0.f, 0.f, 0.f, 0.f};
            #pragma unroll
            for (int ky = 0; ky < 4; ky++) {
                #pragma unroll
                for (int kx = 0; kx < 4; kx++) {
                    int qin = (oy * 2 + ky) * 20 + ox * 2 + kx;
                    short8 a = lds_load8(c1_s + qin * 36 + q * 8);
                    acc = __builtin_amdgcn_mfma_f32_16x16x32_bf16(a, bfr[ky * 4 + kx], acc, 0, 0, 0);
                }
            }
            #pragma unroll
            for (int i = 0; i < 4; i++) {
                int px = t * 16 + q * 4 + i;
                if (px < 81)
                    c2_s[px * 68 + oct * 16 + r] = f2bf(relu_f(acc[i] + bb));
            }
        }
    }
    __syncthreads();

    // ---- conv3: 7x7x64, k=3 s=1; 9 pos x K=64 (2 chunks) ----
    {
        int oct = w;
        short8 bfr[18];
        #pragma unroll
        for (int p = 0; p < 9; p++) {
            #pragma unroll
            for (int h = 0; h < 2; h++)
                bfr[p * 2 + h] = *(const short8*)(W3b + (p * 64 + oct * 16 + r) * 64 + h * 32 + q * 8);
        }
        float bb = b3[oct * 16 + r];
        for (int t = 0; t < 4; t++) {
            int pxa = min(t * 16 + r, 48);
            int oy = pxa / 7, ox = pxa % 7;
            floatx4 acc = {0.f, 0.f, 0.f, 0.f};
            #pragma unroll
            for (int ky = 0; ky < 3; ky++) {
                #pragma unroll
                for (int kx = 0; kx < 3; kx++) {
                    int qin = (oy + ky) * 9 + ox + kx;
                    const ushort_t* ap = c2_s + qin * 68 + q * 8;
                    short8 a0 = lds_load8(ap);
                    short8 a1 = lds_load8(ap + 32);
                    acc = __builtin_amdgcn_mfma_f32_16x16x32_bf16(a0, bfr[(ky * 3 + kx) * 2],     acc, 0, 0, 0);
                    acc = __builtin_amdgcn_mfma_f32_16x16x32_bf16(a1, bfr[(ky * 3 + kx) * 2 + 1], acc, 0, 0, 0);
                }
            }
            #pragma unroll
            for (int i = 0; i < 4; i++) {
                int px = t * 16 + q * 4 + i;
                if (px < 49)
                    out3[(size_t)n * 3136 + px * 64 + oct * 16 + r] = f2bf(relu_f(acc[i] + bb));
            }
        }
    }
}

// ---------------- FC via MFMA: feat[2048][512] = relu(out3 @ Wfc + bfc) ----------------
__global__ __launch_bounds__(256) void fc_mfma_kernel(
    const ushort_t* __restrict__ A, const ushort_t* __restrict__ BT,
    const float* __restrict__ bfc, ushort_t* __restrict__ feat)
{
    int mb = blockIdx.x & 63, nb = blockIdx.x >> 6;   // 64 x 8
    int tid = threadIdx.x;
    int w = tid >> 6, lane = tid & 63;
    int r = lane & 15, q = lane >> 4;
    int m0 = mb * 32 + (w & 1) * 16;
    int n0 = nb * 64 + (w >> 1) * 32;
    const ushort_t* arow  = A  + (size_t)(m0 + r) * 3136 + q * 8;
    const ushort_t* brow0 = BT + (size_t)(n0 + r) * 3136 + q * 8;
    const ushort_t* brow1 = BT + (size_t)(n0 + 16 + r) * 3136 + q * 8;
    floatx4 acc0 = {0.f, 0.f, 0.f, 0.f}, acc1 = {0.f, 0.f, 0.f, 0.f};
    short8 a  = *(const short8*)arow;
    short8 b0 = *(const short8*)brow0;
    short8 b1 = *(const short8*)brow1;
    for (int kk = 1; kk < 98; kk++) {
        short8 an  = *(const short8*)(arow  + kk * 32);
        short8 b0n = *(const short8*)(brow0 + kk * 32);
        short8 b1n = *(const short8*)(brow1 + kk * 32);
        acc0 = __builtin_amdgcn_mfma_f32_16x16x32_bf16(a, b0, acc0, 0, 0, 0);
        acc1 = __builtin_amdgcn_mfma_f32_16x16x32_bf16(a, b1, acc1, 0, 0, 0);
        a = an; b0 = b0n; b1 = b1n;
    }
    acc0 = __builtin_amdgcn_mfma_f32_16x16x32_bf16(a, b0, acc0, 0, 0, 0);
    acc1 = __builtin_amdgcn_mfma_f32_16x16x32_bf16(a, b1, acc1, 0, 0, 0);
    int c0 = n0 + r, c1 = n0 + 16 + r;
    float bb0 = bfc[c0], bb1 = bfc[c1];
    #pragma unroll
    for (int i = 0; i < 4; i++) {
        int row = m0 + q * 4 + i;
        feat[(size_t)row * 512 + c0] = f2bf(relu_f(acc0[i] + bb0));
        feat[(size_t)row * 512 + c1] = f2bf(relu_f(acc1[i] + bb1));
    }
}

// ---------------- gates via MFMA: gx[2048][512] = feat @ Wih[:,:512]^T + onehot + bias ----------------
__global__ __launch_bounds__(256) void gates_mfma_kernel(
    const ushort_t* __restrict__ A, const ushort_t* __restrict__ Wihb,
    const float* __restrict__ Wih, const float* __restrict__ bih,
    const float* __restrict__ bhh, const int* __restrict__ pos,
    float* __restrict__ gx)
{
    int mb = blockIdx.x & 63, nb = blockIdx.x >> 6;   // 64 x 8
    int tid = threadIdx.x;
    int w = tid >> 6, lane = tid & 63;
    int r = lane & 15, q = lane >> 4;
    int m0 = mb * 32 + (w & 1) * 16;
    int n0 = nb * 64 + (w >> 1) * 32;
    const ushort_t* arow  = A    + (size_t)(m0 + r) * 512 + q * 8;
    const ushort_t* brow0 = Wihb + (size_t)(n0 + r) * 512 + q * 8;
    const ushort_t* brow1 = Wihb + (size_t)(n0 + 16 + r) * 512 + q * 8;
    floatx4 acc0 = {0.f, 0.f, 0.f, 0.f}, acc1 = {0.f, 0.f, 0.f, 0.f};
    short8 a  = *(const short8*)arow;
    short8 b0 = *(const short8*)brow0;
    short8 b1 = *(const short8*)brow1;
    for (int kk = 1; kk < 16; kk++) {
        short8 an  = *(const short8*)(arow  + kk * 32);
        short8 b0n = *(const short8*)(brow0 + kk * 32);
        short8 b1n = *(const short8*)(brow1 + kk * 32);
        acc0 = __builtin_amdgcn_mfma_f32_16x16x32_bf16(a, b0, acc0, 0, 0, 0);
        acc1 = __builtin_amdgcn_mfma_f32_16x16x32_bf16(a, b1, acc1, 0, 0, 0);
        a = an; b0 = b0n; b1 = b1n;
    }
    acc0 = __builtin_amdgcn_mfma_f32_16x16x32_bf16(a, b0, acc0, 0, 0, 0);
    acc1 = __builtin_amdgcn_mfma_f32_16x16x32_bf16(a, b1, acc1, 0, 0, 0);
    int j0 = n0 + r, j1 = n0 + 16 + r;
    float bias0 = bih[j0] + bhh[j0];
    float bias1 = bih[j1] + bhh[j1];
    #pragma unroll
    for (int i = 0; i < 4; i++) {
        int row = m0 + q * 4 + i;
        int p0 = pos[2 * row], p1 = pos[2 * row + 1];
        float oh0 = Wih[(size_t)j0 * 532 + 512 + p0] + Wih[(size_t)j0 * 532 + 522 + p1];
        float oh1 = Wih[(size_t)j1 * 532 + 512 + p0] + Wih[(size_t)j1 * 532 + 522 + p1];
        gx[(size_t)row * 512 + j0] = acc0[i] + bias0 + oh0;
        gx[(size_t)row * 512 + j1] = acc1[i] + bias1 + oh1;
    }
}

// ---------------- LSTM: 32 independent blocks (one per batch element) ----------------
__global__ __launch_bounds__(512, 2) void lstm_kernel(
    const float* __restrict__ gx, const float* __restrict__ Whh,
    const int* __restrict__ done, const float* __restrict__ h0,
    const float* __restrict__ c0, ushort_t* __restrict__ hs,
    float* __restrict__ out)
{
    __shared__ __align__(16) float h_s[128];
    __shared__ float gates_s[512];
    int b = blockIdx.x, tid = threadIdx.x;
    int g = tid >> 7, j = tid & 127;

    float w[128];
    const float* wr = Whh + (size_t)(g * 128 + j) * 128;
    #pragma unroll
    for (int k = 0; k < 128; k += 4) {
        float4 v = *(const float4*)(wr + k);
        w[k] = v.x; w[k + 1] = v.y; w[k + 2] = v.z; w[k + 3] = v.w;
    }
    float h = h0[b * 128 + j];
    float c = c0[b * 128 + j];
    const float* gxb = gx + (size_t)b * 512;

    for (int t = 0; t < TT; t++) {
        float m = 1.0f - (float)done[t * 32 + b];
        c *= m;
        if (g == 0) h_s[j] = h * m;
        __syncthreads();
        float acc = 0.0f;
        #pragma unroll
        for (int k = 0; k < 128; k += 4) {
            float4 hv = *(const float4*)&h_s[k];
            acc = fmaf(w[k], hv.x, acc);
            acc = fmaf(w[k + 1], hv.y, acc);
            acc = fmaf(w[k + 2], hv.z, acc);
            acc = fmaf(w[k + 3], hv.w, acc);
        }
        acc += gxb[(size_t)t * 32 * 512 + (g << 7) + j];
        gates_s[(g << 7) + j] = acc;
        __syncthreads();
        float iv = sigmoid_f(gates_s[j]);
        float fv = sigmoid_f(gates_s[128 + j]);
        float gv = tanhf(gates_s[256 + j]);
        float ov = sigmoid_f(gates_s[384 + j]);
        c = fv * c + iv * gv;
        h = ov * tanhf(c);
        if (g == 0) hs[((size_t)t * 32 + b) * 128 + j] = f2bf(h);
    }
    if (g == 0) {
        out[12288 + b * 128 + j] = h;
        out[16384 + b * 128 + j] = c;
    }
}

// ---------------- heads: logits (2048x5), v (2048) ----------------
__global__ __launch_bounds__(256) void heads_kernel(
    const ushort_t* __restrict__ hs, const float* __restrict__ Wp,
    const float* __restrict__ bp, const float* __restrict__ Wv,
    const float* __restrict__ bv, float* __restrict__ out)
{
    int id = blockIdx.x * 256 + threadIdx.x;   // 12288 = 2048*6
    int n = id / 6, q = id % 6;
    const ushort_t* hrow = hs + (size_t)n * 128;
    if (q < 5) {
        float acc = bp[q];
        for (int k = 0; k < 128; k++) acc = fmaf(bf2f(hrow[k]), Wp[k * 5 + q], acc);
        out[n * 5 + q] = acc;
    } else {
        float acc = bv[0];
        for (int k = 0; k < 128; k++) acc = fmaf(bf2f(hrow[k]), Wv[k], acc);
        out[10240 + n] = acc;
    }
}

extern "C" void kernel_launch(void* const* d_in, const int* in_sizes, int n_in,
                              void* d_out, int out_size, void* d_ws, size_t ws_size,
                              hipStream_t stream) {
    const float* image = (const float*)d_in[0];
    const int*   pos   = (const int*)d_in[1];
    const int*   done  = (const int*)d_in[2];
    const float* h0    = (const float*)d_in[3];
    const float* c0    = (const float*)d_in[4];
    const float* W1    = (const float*)d_in[5];
    const float* b1    = (const float*)d_in[6];
    const float* W2    = (const float*)d_in[7];
    const float* b2    = (const float*)d_in[8];
    const float* W3    = (const float*)d_in[9];
    const float* b3    = (const float*)d_in[10];
    const float* Wfc   = (const float*)d_in[11];
    const float* bfc   = (const float*)d_in[12];
    const float* Wih   = (const float*)d_in[13];
    const float* Whh   = (const float*)d_in[14];
    const float* bih   = (const float*)d_in[15];
    const float* bhh   = (const float*)d_in[16];
    const float* Wp    = (const float*)d_in[17];
    const float* bp    = (const float*)d_in[18];
    const float* Wv    = (const float*)d_in[19];
    const float* bv    = (const float*)d_in[20];

    char* ws = (char*)d_ws;
    ushort_t* Wihb = (ushort_t*)(ws + 0);           //   524,288 B
    ushort_t* WfcT = (ushort_t*)(ws + 524288);      // 3,211,264 -> 3,735,552
    ushort_t* W1b  = (ushort_t*)(ws + 3735552);     //    16,384 -> 3,751,936
    ushort_t* W2b  = (ushort_t*)(ws + 3751936);     //    65,536 -> 3,817,472
    ushort_t* W3b  = (ushort_t*)(ws + 3817472);     //    73,728 -> 3,891,200
    ushort_t* out3 = (ushort_t*)(ws + 4194304);     // 12,845,056 -> 17,039,360
    ushort_t* feat = (ushort_t*)(ws + 17039360);    //  2,097,152 -> 19,136,512
    float*    gx   = (float*)(ws + 19136512);       //  4,194,304 -> 23,330,816
    ushort_t* hs   = (ushort_t*)(ws + 23330816);    //    524,288 -> 23,855,104

    float* out = (float*)d_out;

    prep_kernel<<<1024, 256, 0, stream>>>(Wih, Wihb);
    prep_convw_kernel<<<304, 256, 0, stream>>>(W1, W2, W3, W1b, W2b, W3b);
    wfct_kernel<<<392, 256, 0, stream>>>(Wfc, WfcT);
    convs_mfma<<<2048, 256, 0, stream>>>(image, W1b, b1, W2b, b2, W3b, b3, out3);
    fc_mfma_kernel<<<512, 256, 0, stream>>>(out3, WfcT, bfc, feat);
    gates_mfma_kernel<<<512, 256, 0, stream>>>(feat, Wihb, Wih, bih, bhh, pos, gx);
    lstm_kernel<<<32, 512, 0, stream>>>(gx, Whh, done, h0, c0, hs, out);
    heads_kernel<<<48, 256, 0, stream>>>(hs, Wp, bp, Wv, bv, out);
}

// Round 7
// 536.455 us; speedup vs baseline: 6.8412x; 1.0049x over previous
//
#include <hip/hip_runtime.h>

typedef unsigned short ushort_t;
typedef unsigned int uint_t;
typedef __attribute__((ext_vector_type(8))) short short8;
typedef __attribute__((ext_vector_type(4))) short short4v;
typedef __attribute__((ext_vector_type(4))) float floatx4;

__device__ __forceinline__ float bf2f(ushort_t u){
    union { uint_t i; float f; } c; c.i = ((uint_t)u) << 16; return c.f;
}
__device__ __forceinline__ ushort_t f2bf(float x){
    union { float f; uint_t i; } c; c.f = x;
    uint_t i = c.i;
    return (ushort_t)((i + 0x7fffu + ((i >> 16) & 1u)) >> 16);
}
// fast pack of 2 fp32 -> 2 bf16 (round-half-up): 2 adds + v_perm
__device__ __forceinline__ uint_t cvt2fast(float a, float b){
    union { float f; uint_t i; } ca, cb; ca.f = a; cb.f = b;
    uint_t ia = ca.i + 0x8000u, ib = cb.i + 0x8000u;
    return __builtin_amdgcn_perm(ib, ia, 0x07060302u);
}
// 16B fragment from LDS with only 8B alignment guaranteed -> 2x ds_read_b64
__device__ __forceinline__ short8 lds_load8(const ushort_t* p){
    union { short4v h[2]; short8 s; } u;
    u.h[0] = *(const short4v*)p;
    u.h[1] = *(const short4v*)(p + 4);
    return u.s;
}
__device__ __forceinline__ float relu_f(float x){ return fmaxf(x, 0.0f); }
__device__ __forceinline__ float sigmoid_f(float x){ return 1.0f / (1.0f + __expf(-x)); }

#define NT 2048
#define TT 64

// ---------------- prep: Wihb[j][k] = bf16(Wih[j][k]), k<512 ----------------
__global__ __launch_bounds__(256) void prep_kernel(
    const float* __restrict__ Wih, ushort_t* __restrict__ Wihb)
{
    int i = blockIdx.x * 256 + threadIdx.x;   // 262144
    int j = i >> 9, k = i & 511;
    Wihb[i] = f2bf(Wih[j * 532 + k]);
}

// ---------------- prep conv weights: W1b[8][32oc][32k], W2b[16][64oc][32ic], W3b[9][64oc][64ic] ----------------
__global__ __launch_bounds__(256) void prep_convw_kernel(
    const float* __restrict__ W1, const float* __restrict__ W2,
    const float* __restrict__ W3, ushort_t* __restrict__ W1b,
    ushort_t* __restrict__ W2b, ushort_t* __restrict__ W3b)
{
    int i = blockIdx.x * 256 + threadIdx.x;   // 77824 total
    if (i < 8192) {                           // W1b: k = kx*3+ic (24 real, pad 8 zeros)
        int ky = i >> 10, oc = (i >> 5) & 31, k = i & 31;
        float v = 0.0f;
        if (k < 24) { int kx = k / 3, ic = k % 3; v = W1[((ky * 8 + kx) * 3 + ic) * 32 + oc]; }
        W1b[i] = f2bf(v);
        return;
    }
    i -= 8192;
    if (i < 32768) {                          // W2b[kk][oc][ic]
        int kk = i >> 11, oc = (i >> 5) & 63, ic = i & 31;
        W2b[i] = f2bf(W2[(kk * 32 + ic) * 64 + oc]);
        return;
    }
    i -= 32768;
    if (i < 36864) {                          // W3b[p][oc][ic]
        int p = i >> 12, oc = (i >> 6) & 63, ic = i & 63;
        W3b[i] = f2bf(W3[(p * 64 + ic) * 64 + oc]);
    }
}

// ---------------- wfct: Wfc[3136][512] f32 -> WfcT[512][3136] bf16 ----------------
__global__ __launch_bounds__(256) void wfct_kernel(
    const float* __restrict__ Wfc, ushort_t* __restrict__ WfcT)
{
    __shared__ ushort_t t_s[64][65];
    int kb = blockIdx.x % 49, jb = blockIdx.x / 49;   // 49*8 blocks
    int k0 = kb * 64, j0 = jb * 64;
    int jj = threadIdx.x & 63, i4 = threadIdx.x >> 6;
    for (int rr = i4; rr < 64; rr += 4)
        t_s[rr][jj] = f2bf(Wfc[(size_t)(k0 + rr) * 512 + j0 + jj]);
    __syncthreads();
    for (int rr = i4; rr < 64; rr += 4)
        WfcT[(size_t)(j0 + rr) * 3136 + k0 + jj] = t_s[jj][rr];
}

// ---------------- fused convs via MFMA, block per sample ----------------
// conv1 reads image straight from global (L2/L3-resident), cvt in-register;
// only c1/c2 live in LDS (39.8 KB -> 4 blocks/CU).
__global__ __launch_bounds__(256, 4) void convs_mfma(
    const float* __restrict__ img,
    const ushort_t* __restrict__ W1b, const float* __restrict__ b1,
    const ushort_t* __restrict__ W2b, const float* __restrict__ b2,
    const ushort_t* __restrict__ W3b, const float* __restrict__ b3,
    ushort_t* __restrict__ out3)
{
    __shared__ ushort_t c1_s[400 * 36];   // 28,800 B, stride 36 hw (8B-aligned frags)
    __shared__ ushort_t c2_s[81 * 68];    // 11,016 B, stride 68 hw

    int n = blockIdx.x, tid = threadIdx.x;
    int w = tid >> 6, lane = tid & 63;
    int r = lane & 15, q = lane >> 4;

    // ---- conv1: 20x20x32, k=8 s=4; K=32 (kx*3+ic, B-rows zero-padded 24..31) ----
    // wave = px-phase; each wave computes BOTH 16-oc tiles from one A-fragment
    {
        short8 bf0[8], bf1[8];
        #pragma unroll
        for (int ky = 0; ky < 8; ky++) {
            bf0[ky] = *(const short8*)(W1b + (ky * 32 +      r) * 32 + q * 8);
            bf1[ky] = *(const short8*)(W1b + (ky * 32 + 16 + r) * 32 + q * 8);
        }
        float bb0 = b1[r], bb1 = b1[16 + r];
        const float* abase = img + (size_t)n * 21168;
        for (int t = w; t < 25; t += 4) {
            int pxa = t * 16 + r;
            int oy = pxa / 20, ox = pxa % 20;
            floatx4 acc0 = {0.f, 0.f, 0.f, 0.f}, acc1 = {0.f, 0.f, 0.f, 0.f};
            #pragma unroll
            for (int ky = 0; ky < 8; ky++) {
                short8 a = {0,0,0,0,0,0,0,0};
                if (q < 3) {
                    const float* p = abase + ((oy * 4 + ky) * 84 + ox * 4) * 3 + q * 8;
                    float4 f0 = *(const float4*)p;
                    float4 f1 = *(const float4*)(p + 4);
                    union { uint_t u[4]; short8 s; } pk;
                    pk.u[0] = cvt2fast(f0.x, f0.y);
                    pk.u[1] = cvt2fast(f0.z, f0.w);
                    pk.u[2] = cvt2fast(f1.x, f1.y);
                    pk.u[3] = cvt2fast(f1.z, f1.w);
                    a = pk.s;
                }
                acc0 = __builtin_amdgcn_mfma_f32_16x16x32_bf16(a, bf0[ky], acc0, 0, 0, 0);
                acc1 = __builtin_amdgcn_mfma_f32_16x16x32_bf16(a, bf1[ky], acc1, 0, 0, 0);
            }
            int pxs = t * 16 + q * 4;
            #pragma unroll
            for (int i = 0; i < 4; i++) {
                c1_s[(pxs + i) * 36 +      r] = f2bf(relu_f(acc0[i] + bb0));
                c1_s[(pxs + i) * 36 + 16 + r] = f2bf(relu_f(acc1[i] + bb1));
            }
        }
    }
    __syncthreads();

    // ---- conv2: 9x9x64, k=4 s=2; 16 pos x K=32; wave = oc-tile ----
    {
        int oct = w;
        short8 bfr[16];
        #pragma unroll
        for (int kk = 0; kk < 16; kk++)
            bfr[kk] = *(const short8*)(W2b + (kk * 64 + oct * 16 + r) * 32 + q * 8);
        float bb = b2[oct * 16 + r];
        for (int t = 0; t < 6; t++) {
            int pxa = min(t * 16 + r, 80);
            int oy = pxa / 9, ox = pxa % 9;
            floatx4 acc = {0.f, 0.f, 0.f, 0.f};
            #pragma unroll
            for (int ky = 0; ky < 4; ky++) {
                #pragma unroll
                for (int kx = 0; kx < 4; kx++) {
                    int qin = (oy * 2 + ky) * 20 + ox * 2 + kx;
                    short8 a = lds_load8(c1_s + qin * 36 + q * 8);
                    acc = __builtin_amdgcn_mfma_f32_16x16x32_bf16(a, bfr[ky * 4 + kx], acc, 0, 0, 0);
                }
            }
            #pragma unroll
            for (int i = 0; i < 4; i++) {
                int px = t * 16 + q * 4 + i;
                if (px < 81)
                    c2_s[px * 68 + oct * 16 + r] = f2bf(relu_f(acc[i] + bb));
            }
        }
    }
    __syncthreads();

    // ---- conv3: 7x7x64, k=3 s=1; 9 pos x K=64 (2 chunks); wave = oc-tile ----
    {
        int oct = w;
        short8 bfr[18];
        #pragma unroll
        for (int p = 0; p < 9; p++) {
            #pragma unroll
            for (int h = 0; h < 2; h++)
                bfr[p * 2 + h] = *(const short8*)(W3b + (p * 64 + oct * 16 + r) * 64 + h * 32 + q * 8);
        }
        float bb = b3[oct * 16 + r];
        for (int t = 0; t < 4; t++) {
            int pxa = min(t * 16 + r, 48);
            int oy = pxa / 7, ox = pxa % 7;
            floatx4 acc = {0.f, 0.f, 0.f, 0.f};
            #pragma unroll
            for (int ky = 0; ky < 3; ky++) {
                #pragma unroll
                for (int kx = 0; kx < 3; kx++) {
                    int qin = (oy + ky) * 9 + ox + kx;
                    const ushort_t* ap = c2_s + qin * 68 + q * 8;
                    short8 a0 = lds_load8(ap);
                    short8 a1 = lds_load8(ap + 32);
                    acc = __builtin_amdgcn_mfma_f32_16x16x32_bf16(a0, bfr[(ky * 3 + kx) * 2],     acc, 0, 0, 0);
                    acc = __builtin_amdgcn_mfma_f32_16x16x32_bf16(a1, bfr[(ky * 3 + kx) * 2 + 1], acc, 0, 0, 0);
                }
            }
            #pragma unroll
            for (int i = 0; i < 4; i++) {
                int px = t * 16 + q * 4 + i;
                if (px < 49)
                    out3[(size_t)n * 3136 + px * 64 + oct * 16 + r] = f2bf(relu_f(acc[i] + bb));
            }
        }
    }
}

// ---------------- FC via MFMA: feat[2048][512] = relu(out3 @ Wfc + bfc) ----------------
__global__ __launch_bounds__(256) void fc_mfma_kernel(
    const ushort_t* __restrict__ A, const ushort_t* __restrict__ BT,
    const float* __restrict__ bfc, ushort_t* __restrict__ feat)
{
    int mb = blockIdx.x & 63, nb = blockIdx.x >> 6;   // 64 x 8
    int tid = threadIdx.x;
    int w = tid >> 6, lane = tid & 63;
    int r = lane & 15, q = lane >> 4;
    int m0 = mb * 32 + (w & 1) * 16;
    int n0 = nb * 64 + (w >> 1) * 32;
    const ushort_t* arow  = A  + (size_t)(m0 + r) * 3136 + q * 8;
    const ushort_t* brow0 = BT + (size_t)(n0 + r) * 3136 + q * 8;
    const ushort_t* brow1 = BT + (size_t)(n0 + 16 + r) * 3136 + q * 8;
    floatx4 acc0 = {0.f, 0.f, 0.f, 0.f}, acc1 = {0.f, 0.f, 0.f, 0.f};
    short8 a  = *(const short8*)arow;
    short8 b0 = *(const short8*)brow0;
    short8 b1 = *(const short8*)brow1;
    for (int kk = 1; kk < 98; kk++) {
        short8 an  = *(const short8*)(arow  + kk * 32);
        short8 b0n = *(const short8*)(brow0 + kk * 32);
        short8 b1n = *(const short8*)(brow1 + kk * 32);
        acc0 = __builtin_amdgcn_mfma_f32_16x16x32_bf16(a, b0, acc0, 0, 0, 0);
        acc1 = __builtin_amdgcn_mfma_f32_16x16x32_bf16(a, b1, acc1, 0, 0, 0);
        a = an; b0 = b0n; b1 = b1n;
    }
    acc0 = __builtin_amdgcn_mfma_f32_16x16x32_bf16(a, b0, acc0, 0, 0, 0);
    acc1 = __builtin_amdgcn_mfma_f32_16x16x32_bf16(a, b1, acc1, 0, 0, 0);
    int c0 = n0 + r, c1 = n0 + 16 + r;
    float bb0 = bfc[c0], bb1 = bfc[c1];
    #pragma unroll
    for (int i = 0; i < 4; i++) {
        int row = m0 + q * 4 + i;
        feat[(size_t)row * 512 + c0] = f2bf(relu_f(acc0[i] + bb0));
        feat[(size_t)row * 512 + c1] = f2bf(relu_f(acc1[i] + bb1));
    }
}

// ---------------- gates via MFMA: gx[2048][512] = feat @ Wih[:,:512]^T + onehot + bias ----------------
__global__ __launch_bounds__(256) void gates_mfma_kernel(
    const ushort_t* __restrict__ A, const ushort_t* __restrict__ Wihb,
    const float* __restrict__ Wih, const float* __restrict__ bih,
    const float* __restrict__ bhh, const int* __restrict__ pos,
    float* __restrict__ gx)
{
    int mb = blockIdx.x & 63, nb = blockIdx.x >> 6;   // 64 x 8
    int tid = threadIdx.x;
    int w = tid >> 6, lane = tid & 63;
    int r = lane & 15, q = lane >> 4;
    int m0 = mb * 32 + (w & 1) * 16;
    int n0 = nb * 64 + (w >> 1) * 32;
    const ushort_t* arow  = A    + (size_t)(m0 + r) * 512 + q * 8;
    const ushort_t* brow0 = Wihb + (size_t)(n0 + r) * 512 + q * 8;
    const ushort_t* brow1 = Wihb + (size_t)(n0 + 16 + r) * 512 + q * 8;
    floatx4 acc0 = {0.f, 0.f, 0.f, 0.f}, acc1 = {0.f, 0.f, 0.f, 0.f};
    short8 a  = *(const short8*)arow;
    short8 b0 = *(const short8*)brow0;
    short8 b1 = *(const short8*)brow1;
    for (int kk = 1; kk < 16; kk++) {
        short8 an  = *(const short8*)(arow  + kk * 32);
        short8 b0n = *(const short8*)(brow0 + kk * 32);
        short8 b1n = *(const short8*)(brow1 + kk * 32);
        acc0 = __builtin_amdgcn_mfma_f32_16x16x32_bf16(a, b0, acc0, 0, 0, 0);
        acc1 = __builtin_amdgcn_mfma_f32_16x16x32_bf16(a, b1, acc1, 0, 0, 0);
        a = an; b0 = b0n; b1 = b1n;
    }
    acc0 = __builtin_amdgcn_mfma_f32_16x16x32_bf16(a, b0, acc0, 0, 0, 0);
    acc1 = __builtin_amdgcn_mfma_f32_16x16x32_bf16(a, b1, acc1, 0, 0, 0);
    int j0 = n0 + r, j1 = n0 + 16 + r;
    float bias0 = bih[j0] + bhh[j0];
    float bias1 = bih[j1] + bhh[j1];
    #pragma unroll
    for (int i = 0; i < 4; i++) {
        int row = m0 + q * 4 + i;
        int p0 = pos[2 * row], p1 = pos[2 * row + 1];
        float oh0 = Wih[(size_t)j0 * 532 + 512 + p0] + Wih[(size_t)j0 * 532 + 522 + p1];
        float oh1 = Wih[(size_t)j1 * 532 + 512 + p0] + Wih[(size_t)j1 * 532 + 522 + p1];
        gx[(size_t)row * 512 + j0] = acc0[i] + bias0 + oh0;
        gx[(size_t)row * 512 + j1] = acc1[i] + bias1 + oh1;
    }
}

// ---------------- LSTM: 32 independent blocks (one per batch element) ----------------
__global__ __launch_bounds__(512, 2) void lstm_kernel(
    const float* __restrict__ gx, const float* __restrict__ Whh,
    const int* __restrict__ done, const float* __restrict__ h0,
    const float* __restrict__ c0, ushort_t* __restrict__ hs,
    float* __restrict__ out)
{
    __shared__ __align__(16) float h_s[128];
    __shared__ float gates_s[512];
    int b = blockIdx.x, tid = threadIdx.x;
    int g = tid >> 7, j = tid & 127;

    float w[128];
    const float* wr = Whh + (size_t)(g * 128 + j) * 128;
    #pragma unroll
    for (int k = 0; k < 128; k += 4) {
        float4 v = *(const float4*)(wr + k);
        w[k] = v.x; w[k + 1] = v.y; w[k + 2] = v.z; w[k + 3] = v.w;
    }
    float h = h0[b * 128 + j];
    float c = c0[b * 128 + j];
    const float* gxb = gx + (size_t)b * 512;

    for (int t = 0; t < TT; t++) {
        float m = 1.0f - (float)done[t * 32 + b];
        c *= m;
        if (g == 0) h_s[j] = h * m;
        __syncthreads();
        float acc = 0.0f;
        #pragma unroll
        for (int k = 0; k < 128; k += 4) {
            float4 hv = *(const float4*)&h_s[k];
            acc = fmaf(w[k], hv.x, acc);
            acc = fmaf(w[k + 1], hv.y, acc);
            acc = fmaf(w[k + 2], hv.z, acc);
            acc = fmaf(w[k + 3], hv.w, acc);
        }
        acc += gxb[(size_t)t * 32 * 512 + (g << 7) + j];
        gates_s[(g << 7) + j] = acc;
        __syncthreads();
        float iv = sigmoid_f(gates_s[j]);
        float fv = sigmoid_f(gates_s[128 + j]);
        float gv = tanhf(gates_s[256 + j]);
        float ov = sigmoid_f(gates_s[384 + j]);
        c = fv * c + iv * gv;
        h = ov * tanhf(c);
        if (g == 0) hs[((size_t)t * 32 + b) * 128 + j] = f2bf(h);
    }
    if (g == 0) {
        out[12288 + b * 128 + j] = h;
        out[16384 + b * 128 + j] = c;
    }
}

// ---------------- heads: logits (2048x5), v (2048) ----------------
__global__ __launch_bounds__(256) void heads_kernel(
    const ushort_t* __restrict__ hs, const float* __restrict__ Wp,
    const float* __restrict__ bp, const float* __restrict__ Wv,
    const float* __restrict__ bv, float* __restrict__ out)
{
    int id = blockIdx.x * 256 + threadIdx.x;   // 12288 = 2048*6
    int n = id / 6, q = id % 6;
    const ushort_t* hrow = hs + (size_t)n * 128;
    if (q < 5) {
        float acc = bp[q];
        for (int k = 0; k < 128; k++) acc = fmaf(bf2f(hrow[k]), Wp[k * 5 + q], acc);
        out[n * 5 + q] = acc;
    } else {
        float acc = bv[0];
        for (int k = 0; k < 128; k++) acc = fmaf(bf2f(hrow[k]), Wv[k], acc);
        out[10240 + n] = acc;
    }
}

extern "C" void kernel_launch(void* const* d_in, const int* in_sizes, int n_in,
                              void* d_out, int out_size, void* d_ws, size_t ws_size,
                              hipStream_t stream) {
    const float* image = (const float*)d_in[0];
    const int*   pos   = (const int*)d_in[1];
    const int*   done  = (const int*)d_in[2];
    const float* h0    = (const float*)d_in[3];
    const float* c0    = (const float*)d_in[4];
    const float* W1    = (const float*)d_in[5];
    const float* b1    = (const float*)d_in[6];
    const float* W2    = (const float*)d_in[7];
    const float* b2    = (const float*)d_in[8];
    const float* W3    = (const float*)d_in[9];
    const float* b3    = (const float*)d_in[10];
    const float* Wfc   = (const float*)d_in[11];
    const float* bfc   = (const float*)d_in[12];
    const float* Wih   = (const float*)d_in[13];
    const float* Whh   = (const float*)d_in[14];
    const float* bih   = (const float*)d_in[15];
    const float* bhh   = (const float*)d_in[16];
    const float* Wp    = (const float*)d_in[17];
    const float* bp    = (const float*)d_in[18];
    const float* Wv    = (const float*)d_in[19];
    const float* bv    = (const float*)d_in[20];

    char* ws = (char*)d_ws;
    ushort_t* Wihb = (ushort_t*)(ws + 0);           //   524,288 B
    ushort_t* WfcT = (ushort_t*)(ws + 524288);      // 3,211,264 -> 3,735,552
    ushort_t* W1b  = (ushort_t*)(ws + 3735552);     //    16,384 -> 3,751,936
    ushort_t* W2b  = (ushort_t*)(ws + 3751936);     //    65,536 -> 3,817,472
    ushort_t* W3b  = (ushort_t*)(ws + 3817472);     //    73,728 -> 3,891,200
    ushort_t* out3 = (ushort_t*)(ws + 4194304);     // 12,845,056 -> 17,039,360
    ushort_t* feat = (ushort_t*)(ws + 17039360);    //  2,097,152 -> 19,136,512
    float*    gx   = (float*)(ws + 19136512);       //  4,194,304 -> 23,330,816
    ushort_t* hs   = (ushort_t*)(ws + 23330816);    //    524,288 -> 23,855,104

    float* out = (float*)d_out;

    prep_kernel<<<1024, 256, 0, stream>>>(Wih, Wihb);
    prep_convw_kernel<<<304, 256, 0, stream>>>(W1, W2, W3, W1b, W2b, W3b);
    wfct_kernel<<<392, 256, 0, stream>>>(Wfc, WfcT);
    convs_mfma<<<2048, 256, 0, stream>>>(image, W1b, b1, W2b, b2, W3b, b3, out3);
    fc_mfma_kernel<<<512, 256, 0, stream>>>(out3, WfcT, bfc, feat);
    gates_mfma_kernel<<<512, 256, 0, stream>>>(feat, Wihb, Wih, bih, bhh, pos, gx);
    lstm_kernel<<<32, 512, 0, stream>>>(gx, Whh, done, h0, c0, hs, out);
    heads_kernel<<<48, 256, 0, stream>>>(hs, Wp, bp, Wv, bv, out);
}